// Round 4
// baseline (479.130 us; speedup 1.0000x reference)
//
#include <hip/hip_runtime.h>
#include <hip/hip_bf16.h>

// TrajectoryDecoder: B=8192 LSTM, T=128, H=128, CTX=256, IN_DIM=132.
// R14: producer/consumer wave specialization.
// R13 post-mortem: phase-shifting groups WITHIN a wave cannot overlap
// MFMA and VALU because MFMA blocks its issuing wave; overlap is only
// cross-wave (m114), and R13's waves ran in lockstep -> VALUBusy stuck
// at 49%, dur 260us. Fix: role-split the 8 waves.
//  - Waves 0-3 (GEMM): hold Wf for 32 H-cols x 4 gates (128 VGPRs),
//    per phase: 4 A-frag b128 reads, 32 MFMAs, write gates as packed
//    {i,f,g,o} f32x4 to LDS (pad-129 rows -> ~conflict-free).
//  - Waves 4-7 (EW): hold cst[2][8] + gate_static[2][8] f32x4 + wps in
//    REGISTERS; per phase read 8 gate f32x4, do all trans/VALU, write h.
//  - wave->SIMD = w%4 pairs one GEMM wave with one EW wave per SIMD:
//    EW fills the VALU while the GEMM wave blocks on MFMA, and the MFMA
//    pipe runs while EW trans-chains issue.
// Same A/B phase-shift pipeline as R13 (gates produced in phase p are
// consumed by EW in phase p+1), ONE barrier/phase, single h buffer
// (disjoint row ranges). launch_bounds(512,2) -> 256-reg cap, ~190 used.
// LDS 97.5KB (gates 66K + c0-xfer 16K + h 8.7K + wof/p0/pw0).

#define HDIM 128
#define CTX_DIM 256
#define T_FRAMES 128
#define BB 32     // batch rows per block
#define STR 136   // h row stride (elements); 272B rows keep 16B alignment
#define GPAD 129  // gate buffer row stride in f32x4 units (pad vs 128)

typedef __bf16 bf16x8 __attribute__((ext_vector_type(8)));
typedef float  f32x4  __attribute__((ext_vector_type(4)));

union frag_u {
  bf16x8 v;
  unsigned short s[8];
  uint4 u4;
};

#if __has_builtin(__builtin_amdgcn_exp2f)
#define EXP2(x) __builtin_amdgcn_exp2f(x)
#else
#define EXP2(x) __expf((x) * 0.6931471805599453f)
#endif
#define RCP(x) __builtin_amdgcn_rcpf(x)

__device__ __forceinline__ unsigned short f2bf(float x) {
  unsigned u = __builtin_bit_cast(unsigned, x);
  u += 0x7FFFu + ((u >> 16) & 1u);          // RNE to bf16
  return (unsigned short)(u >> 16);
}
__device__ __forceinline__ float bf2f(unsigned short h) {
  unsigned u = ((unsigned)h) << 16;
  return __builtin_bit_cast(float, u);
}
template<int CTRL>
__device__ __forceinline__ float dpp_mov(float x) {
  return __builtin_bit_cast(float,
    __builtin_amdgcn_mov_dpp(__builtin_bit_cast(int, x), CTRL, 0xF, 0xF, true));
}
// sum over the 16-lane row group (setup-only)
__device__ __forceinline__ float row_reduce16(float v) {
  v += dpp_mov<0xB1>(v);     // quad_perm xor1
  v += dpp_mov<0x4E>(v);     // quad_perm xor2
  v += dpp_mov<0x124>(v);    // row_ror:4
  v += dpp_mov<0x128>(v);    // row_ror:8
  return v;
}

template<int N> struct Int { static constexpr int value = N; };

#define MFMA(a, b, c) __builtin_amdgcn_mfma_f32_16x16x32_bf16((a), (b), (c), 0, 0, 0)

__global__ __launch_bounds__(512, 2) void traj_lstm(
    const float* __restrict__ ctx, const float* __restrict__ enc,
    const float* __restrict__ ball,
    const float* __restrict__ Wh, const float* __restrict__ bh,
    const float* __restrict__ Wc, const float* __restrict__ bc,
    const float* __restrict__ W_ih, const float* __restrict__ W_hh,
    const float* __restrict__ b_ih, const float* __restrict__ b_hh,
    const float* __restrict__ Wo, const float* __restrict__ bo,
    float* __restrict__ outp)
{
  __shared__ __align__(16) char sh_arena[2 * 16 * GPAD * 16];  // 66048 B
  __shared__ __align__(16) float sh_cb[BB * HDIM];             // c0 xfer (16 KB)
  __shared__ __align__(16) __bf16 sh_h[BB * STR];              // h single buffer (8.7 KB)
  __shared__ __align__(16) uint4 sh_wof[4 * 64];               // Wo B-frags (4 KB)
  __shared__ float sh_pw0[8][BB * 2];     // setup pred partials (2 KB)
  __shared__ float sh_p0[BB * 2];         // virtual pred_{-1} for t=0 correction

  unsigned short* sh_sA = (unsigned short*)sh_arena;           // setup hi (16.9 KB)
  unsigned short* sh_sB = sh_sA + BB * 264;                    // setup lo (16.9 KB)
  f32x4* gs  = (f32x4*)sh_arena;                               // setup gstatic xfer [row*128+hcol]
  f32x4* gbA = (f32x4*)sh_arena;                               // gates A [16][GPAD]
  f32x4* gbB = (f32x4*)(sh_arena + 16 * GPAD * 16);            // gates B [16][GPAD]

  const int tid  = threadIdx.x;
  const int w    = tid >> 6;
  const int l    = tid & 63;
  const int q    = l >> 4;
  const int c16  = l & 15;
  const int colH = w * 16 + c16;       // setup col mapping (all 8 waves)
  const int rbase = blockIdx.x * BB;

  // EW-wave lane mapping (waves 4-7): hcol = (w-4)*32 + (l&31), rows = halfE*8+r
  const int hcE   = ((w - 4) << 5) + (l & 31);
  const int halfE = l >> 5;

  const float Lc = 1.4426950408889634f;          // log2(e)
  const float SG[4] = {Lc, Lc, 2.f * Lc, Lc};    // i, f, g, o exp2 prescales
  const float bo0 = bo[0], bo1 = bo[1];
  const float wo0 = Wo[colH], wo1 = Wo[HDIM + colH];

  // feedback weights per gate at colH (setup bias only)
  float wp0[4], wp1[4];
  #pragma unroll
  for (int g = 0; g < 4; ++g) {
    wp0[g] = W_ih[(size_t)(g * HDIM + colH) * 132 + 0];
    wp1[g] = W_ih[(size_t)(g * HDIM + colH) * 132 + 1];
  }

  // ---- Wo B-fragments for the pred MFMA -> LDS (wave 0 reads in-loop) ----
  #pragma unroll
  for (int kt = 0; kt < 4; ++kt) {
    frag_u wf;
    #pragma unroll
    for (int j = 0; j < 8; ++j) {
      float x = (c16 < 2) ? Wo[c16 * HDIM + kt * 32 + q * 8 + j] : 0.f;
      wf.s[j] = f2bf(x);
    }
    if (w == 0) sh_wof[kt * 64 + l] = wf.u4;
  }

  // ---- stage context rows (32 rows, hi/lo bf16, stride 264) ----
  for (int e = tid; e < BB * 256; e += 512) {
    int row = e >> 8, col = e & 255;
    float x = ctx[(size_t)(rbase + row) * CTX_DIM + col];
    unsigned short hb = f2bf(x);
    sh_sA[row * 264 + col] = hb;
    sh_sB[row * 264 + col] = f2bf(x - bf2f(hb));
  }
  __syncthreads();

  // ---- h0/c0 = ctx @ Wh.T/Wc.T + bias (3-product split, K=256, 2 groups) ----
  {
    f32x4 aH[2] = {{0.f,0.f,0.f,0.f},{0.f,0.f,0.f,0.f}};
    f32x4 aC[2] = {{0.f,0.f,0.f,0.f},{0.f,0.f,0.f,0.f}};
    #pragma unroll
    for (int kt = 0; kt < 8; ++kt) {
      frag_u Ahi[2], Alo[2];
      #pragma unroll
      for (int rt = 0; rt < 2; ++rt) {
        Ahi[rt].u4 = *(const uint4*)&sh_sA[(rt * 16 + c16) * 264 + kt * 32 + q * 8];
        Alo[rt].u4 = *(const uint4*)&sh_sB[(rt * 16 + c16) * 264 + kt * 32 + q * 8];
      }
      frag_u bhi, blo;
      {
        const float* wr = Wh + (size_t)colH * CTX_DIM + kt * 32 + q * 8;
        float4 f0 = *(const float4*)wr;
        float4 f1 = *(const float4*)(wr + 4);
        float ff[8] = {f0.x, f0.y, f0.z, f0.w, f1.x, f1.y, f1.z, f1.w};
        #pragma unroll
        for (int j = 0; j < 8; ++j) {
          unsigned short hb = f2bf(ff[j]);
          bhi.s[j] = hb;
          blo.s[j] = f2bf(ff[j] - bf2f(hb));
        }
      }
      #pragma unroll
      for (int rt = 0; rt < 2; ++rt) {
        aH[rt] = MFMA(Ahi[rt].v, bhi.v, aH[rt]);
        aH[rt] = MFMA(Alo[rt].v, bhi.v, aH[rt]);
        aH[rt] = MFMA(Ahi[rt].v, blo.v, aH[rt]);
      }
      {
        const float* wr = Wc + (size_t)colH * CTX_DIM + kt * 32 + q * 8;
        float4 f0 = *(const float4*)wr;
        float4 f1 = *(const float4*)(wr + 4);
        float ff[8] = {f0.x, f0.y, f0.z, f0.w, f1.x, f1.y, f1.z, f1.w};
        #pragma unroll
        for (int j = 0; j < 8; ++j) {
          unsigned short hb = f2bf(ff[j]);
          bhi.s[j] = hb;
          blo.s[j] = f2bf(ff[j] - bf2f(hb));
        }
      }
      #pragma unroll
      for (int rt = 0; rt < 2; ++rt) {
        aC[rt] = MFMA(Ahi[rt].v, bhi.v, aC[rt]);
        aC[rt] = MFMA(Alo[rt].v, bhi.v, aC[rt]);
        aC[rt] = MFMA(Ahi[rt].v, blo.v, aC[rt]);
      }
    }
    float bhv = bh[colH], bcv = bc[colH];
    float pp0[8][2];
    #pragma unroll
    for (int rt = 0; rt < 2; ++rt) {
      #pragma unroll
      for (int r = 0; r < 4; ++r) {
        int row = rt * 16 + q * 4 + r;
        float h0v = aH[rt][r] + bhv;
        sh_h[row * STR + colH] = (__bf16)h0v;
        sh_cb[row * HDIM + colH] = aC[rt][r] + bcv;   // c0 -> xfer buffer
        pp0[rt * 4 + r][0] = h0v * wo0;
        pp0[rt * 4 + r][1] = h0v * wo1;
      }
    }
    #pragma unroll
    for (int m = 0; m < 8; ++m) {
      pp0[m][0] = row_reduce16(pp0[m][0]);
      pp0[m][1] = row_reduce16(pp0[m][1]);
    }
    if (c16 == 0) {
      #pragma unroll
      for (int rt = 0; rt < 2; ++rt)
        #pragma unroll
        for (int r = 0; r < 4; ++r) {
          sh_pw0[w][(rt * 16 + q * 4 + r) * 2 + 0] = pp0[rt * 4 + r][0];
          sh_pw0[w][(rt * 16 + q * 4 + r) * 2 + 1] = pp0[rt * 4 + r][1];
        }
    }
  }
  __syncthreads();   // sA/sB reuse + pw0 visibility

  // ---- stage static_in = [ball(2), enc(128), pad] (32 rows, stride 168) ----
  for (int e = tid; e < BB * 168; e += 512) {
    int row = e / 168, col = e - row * 168;
    float x = (col < 2) ? ball[(size_t)(rbase + row) * 2 + col]
            : (col < 130) ? enc[(size_t)(rbase + row) * 128 + (col - 2)] : 0.f;
    unsigned short hb = f2bf(x);
    sh_sA[row * 168 + col] = hb;
    sh_sB[row * 168 + col] = f2bf(x - bf2f(hb));
  }
  // virtual pred_{-1} = h0 @ Wo.T + bo (t=0 feedback correction)
  if (tid < BB * 2) {
    float s = (tid & 1) ? bo1 : bo0;
    #pragma unroll
    for (int w2 = 0; w2 < 8; ++w2) s += sh_pw0[w2][tid];
    sh_p0[tid] = s;
  }
  __syncthreads();

  // ---- gate_static (3-product, K=160, SG-scaled) + biases -> registers ----
  f32x4 gacc[2][4] = {{{0.f,0.f,0.f,0.f},{0.f,0.f,0.f,0.f},{0.f,0.f,0.f,0.f},{0.f,0.f,0.f,0.f}},
                      {{0.f,0.f,0.f,0.f},{0.f,0.f,0.f,0.f},{0.f,0.f,0.f,0.f},{0.f,0.f,0.f,0.f}}};
  #pragma unroll
  for (int kt = 0; kt < 5; ++kt) {
    frag_u Ahi[2], Alo[2];
    #pragma unroll
    for (int rt = 0; rt < 2; ++rt) {
      Ahi[rt].u4 = *(const uint4*)&sh_sA[(rt * 16 + c16) * 168 + kt * 32 + q * 8];
      Alo[rt].u4 = *(const uint4*)&sh_sB[(rt * 16 + c16) * 168 + kt * 32 + q * 8];
    }
    #pragma unroll
    for (int g = 0; g < 4; ++g) {
      frag_u bhi, blo;
      #pragma unroll
      for (int j = 0; j < 8; ++j) {
        int kk = kt * 32 + q * 8 + j;
        float x = (kk < 130) ? SG[g] * W_ih[(size_t)(g * HDIM + colH) * 132 + 2 + kk] : 0.f;
        unsigned short hb = f2bf(x);
        bhi.s[j] = hb;
        blo.s[j] = f2bf(x - bf2f(hb));
      }
      #pragma unroll
      for (int rt = 0; rt < 2; ++rt) {
        gacc[rt][g] = MFMA(Ahi[rt].v, bhi.v, gacc[rt][g]);
        gacc[rt][g] = MFMA(Alo[rt].v, bhi.v, gacc[rt][g]);
        gacc[rt][g] = MFMA(Ahi[rt].v, blo.v, gacc[rt][g]);
      }
    }
  }
  #pragma unroll
  for (int g = 0; g < 4; ++g) {
    int colG = g * HDIM + colH;
    float bb = SG[g] * (b_ih[colG] + b_hh[colG] + bo0 * wp0[g] + bo1 * wp1[g]);
    #pragma unroll
    for (int rt = 0; rt < 2; ++rt)
      #pragma unroll
      for (int r = 0; r < 4; ++r) gacc[rt][g][r] += bb;
  }
  __syncthreads();   // all waves done reading sA/sB -> arena becomes gs

  // ---- redistribute gate_static: colH layout -> [row][hcol] packed f32x4 ----
  #pragma unroll
  for (int rt = 0; rt < 2; ++rt)
    #pragma unroll
    for (int r = 0; r < 4; ++r) {
      f32x4 vv = {gacc[rt][0][r], gacc[rt][1][r], gacc[rt][2][r], gacc[rt][3][r]};
      gs[(rt * 16 + q * 4 + r) * HDIM + colH] = vv;
    }
  __syncthreads();

  // ---- EW waves pull their per-lane state; GEMM waves fill Wf ----
  f32x4 gstatE[2][8];      // [group][r]  (EW waves)
  float cstE[2][8];        // c state     (EW waves)
  float wpsE0[4], wpsE1[4];
  frag_u Wf[4][2][4];      // [gate][ctl][kt]  (GEMM waves, 128 VGPRs)
  if (w >= 4) {
    #pragma unroll
    for (int G2 = 0; G2 < 2; ++G2)
      #pragma unroll
      for (int r = 0; r < 8; ++r) {
        int row = G2 * 16 + halfE * 8 + r;
        gstatE[G2][r] = gs[row * HDIM + hcE];
        cstE[G2][r]   = sh_cb[row * HDIM + hcE];
      }
    #pragma unroll
    for (int g = 0; g < 4; ++g) {
      wpsE0[g] = SG[g] * W_ih[(size_t)(g * HDIM + hcE) * 132 + 0];
      wpsE1[g] = SG[g] * W_ih[(size_t)(g * HDIM + hcE) * 132 + 1];
    }
  } else {
    // W_eff = SG[g]*(W_hh + wp0*Wo0 + wp1*Wo1) for cols [w*32, w*32+32)
    #pragma unroll
    for (int ctl = 0; ctl < 2; ++ctl) {
      const int colW = w * 32 + ctl * 16 + c16;
      float wpA[4], wpB[4];
      #pragma unroll
      for (int g = 0; g < 4; ++g) {
        wpA[g] = W_ih[(size_t)(g * HDIM + colW) * 132 + 0];
        wpB[g] = W_ih[(size_t)(g * HDIM + colW) * 132 + 1];
      }
      #pragma unroll
      for (int kt = 0; kt < 4; ++kt) {
        const float* w0p = Wo + kt * 32 + q * 8;
        const float* w1p = Wo + HDIM + kt * 32 + q * 8;
        float4 a0 = *(const float4*)w0p, a1 = *(const float4*)(w0p + 4);
        float4 b0 = *(const float4*)w1p, b1 = *(const float4*)(w1p + 4);
        float wo0v[8] = {a0.x, a0.y, a0.z, a0.w, a1.x, a1.y, a1.z, a1.w};
        float wo1v[8] = {b0.x, b0.y, b0.z, b0.w, b1.x, b1.y, b1.z, b1.w};
        #pragma unroll
        for (int g = 0; g < 4; ++g) {
          const float* wr = W_hh + (size_t)(g * HDIM + colW) * HDIM + kt * 32 + q * 8;
          float4 f0 = *(const float4*)wr;
          float4 f1 = *(const float4*)(wr + 4);
          float ff[8] = {f0.x, f0.y, f0.z, f0.w, f1.x, f1.y, f1.z, f1.w};
          #pragma unroll
          for (int j = 0; j < 8; ++j)
            Wf[g][ctl][kt].s[j] = f2bf(SG[g] * (ff[j] + wpA[g] * wo0v[j] + wpB[g] * wo1v[j]));
        }
      }
    }
  }
  __syncthreads();   // gs consumed -> arena becomes gate buffers

  // ---- time loop: producer/consumer phases, ONE barrier per phase ----
  // P(G,t): GEMM waves compute gates_G(t) from h_G(t) -> gbuf[G];
  //         EW waves consume gates_E (written last phase) -> h_E;
  //         wave 0 also computes pred[t-1] rows G from the same A-frags.
  auto phase = [&](auto GC, int t, bool doEW, bool corr, bool doPred) {
    constexpr int G = decltype(GC)::value;
    constexpr int E = 1 - G;
    if (w < 4) {
      frag_u A[4];
      #pragma unroll
      for (int kt = 0; kt < 4; ++kt)
        A[kt].u4 = *(const uint4*)&sh_h[(G * 16 + c16) * STR + kt * 32 + q * 8];
      f32x4 acc[4][2];
      #pragma unroll
      for (int g = 0; g < 4; ++g)
        #pragma unroll
        for (int ctl = 0; ctl < 2; ++ctl)
          acc[g][ctl] = (f32x4){0.f, 0.f, 0.f, 0.f};
      #pragma unroll
      for (int kt = 0; kt < 4; ++kt)
        #pragma unroll
        for (int g = 0; g < 4; ++g)
          #pragma unroll
          for (int ctl = 0; ctl < 2; ++ctl)
            acc[g][ctl] = MFMA(A[kt].v, Wf[g][ctl][kt].v, acc[g][ctl]);
      f32x4* gb = (G == 0) ? gbA : gbB;
      #pragma unroll
      for (int ctl = 0; ctl < 2; ++ctl)
        #pragma unroll
        for (int r = 0; r < 4; ++r) {
          f32x4 vv = {acc[0][ctl][r], acc[1][ctl][r], acc[2][ctl][r], acc[3][ctl][r]};
          gb[(q * 4 + r) * GPAD + (w * 32 + ctl * 16 + c16)] = vv;
        }
      if (doPred && w == 0) {
        f32x4 accP = {0.f, 0.f, 0.f, 0.f};
        #pragma unroll
        for (int kt = 0; kt < 4; ++kt) {
          frag_u wof;
          wof.u4 = sh_wof[kt * 64 + l];
          accP = MFMA(A[kt].v, wof.v, accP);
        }
        if (c16 < 2) {
          const float bov = c16 ? bo1 : bo0;
          #pragma unroll
          for (int r = 0; r < 4; ++r)
            outp[(size_t)(rbase + G * 16 + q * 4 + r) * (T_FRAMES * 2) + (t - 1) * 2 + c16] = accP[r] + bov;
        }
      }
    } else if (doEW) {
      f32x4* gb = (E == 0) ? gbA : gbB;
      #pragma unroll
      for (int r = 0; r < 8; ++r) {
        const int row = halfE * 8 + r;
        f32x4 gt = gb[row * GPAD + hcE];
        gt += gstatE[E][r];
        if (corr) {   // gates at t=0: remove folded pred_{-1} feedback (scaled)
          float2 p0r = *(const float2*)&sh_p0[(E * 16 + row) * 2];
          #pragma unroll
          for (int g = 0; g < 4; ++g)
            gt[g] -= p0r.x * wpsE0[g] + p0r.y * wpsE1[g];
        }
        float ei = EXP2(-gt[0]);          // e^{-i}
        float ef = EXP2(-gt[1]);          // e^{-f}
        float eg = EXP2(-gt[2]);          // e^{-2g}
        float eo = EXP2(-gt[3]);          // e^{-o}
        float t1 = (1.f + ei) * (1.f + eg);
        float pf = 1.f + ef;
        float num = cstE[E][r] * t1 + (1.f - eg) * pf;
        float cv = num * RCP(t1 * pf);
        cstE[E][r] = cv;
        float cc = fmaxf(cv, -15.f);      // only -inf side can overflow
        float ec = EXP2(cc * (-2.f * 1.4426950408889634f));
        float hv = (1.f - ec) * RCP((1.f + eo) * (1.f + ec));
        sh_h[(E * 16 + row) * STR + hcE] = (__bf16)hv;
      }
    }
    __syncthreads();
  };

  phase(Int<0>{}, 0, false, false, false);  // gates_A(0)
  phase(Int<1>{}, 0, true,  true,  false);  // gates_B(0); ew A(0)+corr -> h_A(1)
  phase(Int<0>{}, 1, true,  true,  true);   // gates_A(1); ew B(0)+corr -> h_B(1); pred[0]A
  phase(Int<1>{}, 1, true,  false, true);   // gates_B(1); ew A(1) -> h_A(2); pred[0]B
  for (int t = 2; t <= 127; ++t) {
    phase(Int<0>{}, t, true, false, true);  // gates_A(t); ew B(t-1) -> h_B(t); pred[t-1]A
    phase(Int<1>{}, t, true, false, true);  // gates_B(t); ew A(t)   -> h_A(t+1); pred[t-1]B
  }

  // ---- epilogue: ew B(127) -> h_B(128), then pred[127] (wave 0) ----
  if (w >= 4) {
    #pragma unroll
    for (int r = 0; r < 8; ++r) {
      const int row = halfE * 8 + r;
      f32x4 gt = gbB[row * GPAD + hcE];
      gt += gstatE[1][r];
      float ei = EXP2(-gt[0]);
      float ef = EXP2(-gt[1]);
      float eg = EXP2(-gt[2]);
      float eo = EXP2(-gt[3]);
      float t1 = (1.f + ei) * (1.f + eg);
      float pf = 1.f + ef;
      float num = cstE[1][r] * t1 + (1.f - eg) * pf;
      float cv = num * RCP(t1 * pf);
      float cc = fmaxf(cv, -15.f);
      float ec = EXP2(cc * (-2.f * 1.4426950408889634f));
      float hv = (1.f - ec) * RCP((1.f + eo) * (1.f + ec));
      sh_h[(16 + row) * STR + hcE] = (__bf16)hv;
    }
  }
  __syncthreads();

  if (w == 0) {
    #pragma unroll
    for (int G2 = 0; G2 < 2; ++G2) {
      f32x4 accP = {0.f, 0.f, 0.f, 0.f};
      #pragma unroll
      for (int kt = 0; kt < 4; ++kt) {
        frag_u A, wof;
        A.u4 = *(const uint4*)&sh_h[(G2 * 16 + c16) * STR + kt * 32 + q * 8];
        wof.u4 = sh_wof[kt * 64 + l];
        accP = MFMA(A.v, wof.v, accP);
      }
      if (c16 < 2) {
        const float bov = c16 ? bo1 : bo0;
        #pragma unroll
        for (int r = 0; r < 4; ++r)
          outp[(size_t)(rbase + G2 * 16 + q * 4 + r) * (T_FRAMES * 2) + 127 * 2 + c16] = accP[r] + bov;
      }
    }
  }
}

extern "C" void kernel_launch(void* const* d_in, const int* in_sizes, int n_in,
                              void* d_out, int out_size, void* d_ws, size_t ws_size,
                              hipStream_t stream) {
  (void)in_sizes; (void)n_in; (void)d_ws; (void)ws_size; (void)out_size;
  const float* ctx  = (const float*)d_in[0];
  const float* enc  = (const float*)d_in[1];
  const float* ball = (const float*)d_in[2];
  // d_in[3] = max_frames (always 128)
  const float* Wh   = (const float*)d_in[4];
  const float* bh   = (const float*)d_in[5];
  const float* Wc   = (const float*)d_in[6];
  const float* bc   = (const float*)d_in[7];
  const float* W_ih = (const float*)d_in[8];
  const float* W_hh = (const float*)d_in[9];
  const float* b_ih = (const float*)d_in[10];
  const float* b_hh = (const float*)d_in[11];
  const float* Wo   = (const float*)d_in[12];
  const float* bo   = (const float*)d_in[13];
  float* outp = (float*)d_out;

  dim3 grid(256), block(512);
  traj_lstm<<<grid, block, 0, stream>>>(ctx, enc, ball, Wh, bh, Wc, bc,
                                        W_ih, W_hh, b_ih, b_hh, Wo, bo, outp);
}

// Round 5
// 345.476 us; speedup vs baseline: 1.3869x; 1.3869x over previous
//
#include <hip/hip_runtime.h>
#include <hip/hip_bf16.h>

// TrajectoryDecoder: B=8192 LSTM, T=128, H=128, CTX=256, IN_DIM=132.
// R15 = R13 + wave-order swap (anti-lockstep).
// R14 post-mortem: producer/consumer split spilled (Wf alone = 128 VGPRs on
// GEMM waves; WRITE_SIZE 38->82MB) and added 128KB/step LDS gate traffic ->
// 440us. Dead end. R13 (260us) already holds two independent streams per
// wave: MFMA(G,t) and EW(E) are data-independent inside a phase; its only
// flaw is both waves per SIMD run them in the SAME order -> lockstep
// all-MFMA then all-EW. Fix costs nothing: waves 0-3 run [MFMA -> EW],
// waves 4-7 run [EW -> MFMA]. Wave w and w+4 share SIMD w%4, so each SIMD
// always has one wave feeding the MFMA pipe and one feeding VALU/trans
// (m114 cross-wave overlap), no occupancy/register/LDS change.
// Correctness: EW(E) writes disjoint h-rows (or the other buffer) from
// MFMA(G)'s reads; cross-wave visibility still guarded by the phase barrier.
// Keeps R13/R10 structure: 512 thr, 1 block/CU, launch_bounds(512,1),
// exp2-prescaled gates SG={L,L,2L,L}, 7 trans/elem, MFMA C-seed, t=0 corr.

#define HDIM 128
#define CTX_DIM 256
#define T_FRAMES 128
#define BB 32     // batch rows per block
#define STR 136   // h row stride (elements); 272B rows keep 16B alignment

typedef __bf16 bf16x8 __attribute__((ext_vector_type(8)));
typedef float  f32x4  __attribute__((ext_vector_type(4)));

union frag_u {
  bf16x8 v;
  unsigned short s[8];
  uint4 u4;
};

#if __has_builtin(__builtin_amdgcn_exp2f)
#define EXP2(x) __builtin_amdgcn_exp2f(x)
#else
#define EXP2(x) __expf((x) * 0.6931471805599453f)
#endif
#define RCP(x) __builtin_amdgcn_rcpf(x)

__device__ __forceinline__ unsigned short f2bf(float x) {
  unsigned u = __builtin_bit_cast(unsigned, x);
  u += 0x7FFFu + ((u >> 16) & 1u);          // RNE to bf16
  return (unsigned short)(u >> 16);
}
__device__ __forceinline__ float bf2f(unsigned short h) {
  unsigned u = ((unsigned)h) << 16;
  return __builtin_bit_cast(float, u);
}
template<int CTRL>
__device__ __forceinline__ float dpp_mov(float x) {
  return __builtin_bit_cast(float,
    __builtin_amdgcn_mov_dpp(__builtin_bit_cast(int, x), CTRL, 0xF, 0xF, true));
}
// sum over the 16-lane row group (setup-only)
__device__ __forceinline__ float row_reduce16(float v) {
  v += dpp_mov<0xB1>(v);     // quad_perm xor1
  v += dpp_mov<0x4E>(v);     // quad_perm xor2
  v += dpp_mov<0x124>(v);    // row_ror:4
  v += dpp_mov<0x128>(v);    // row_ror:8
  return v;
}

template<int N> struct Int { static constexpr int value = N; };

#define MFMA(a, b, c) __builtin_amdgcn_mfma_f32_16x16x32_bf16((a), (b), (c), 0, 0, 0)

__global__ __launch_bounds__(512, 1) void traj_lstm(
    const float* __restrict__ ctx, const float* __restrict__ enc,
    const float* __restrict__ ball,
    const float* __restrict__ Wh, const float* __restrict__ bh,
    const float* __restrict__ Wc, const float* __restrict__ bc,
    const float* __restrict__ W_ih, const float* __restrict__ W_hh,
    const float* __restrict__ b_ih, const float* __restrict__ b_hh,
    const float* __restrict__ Wo, const float* __restrict__ bo,
    float* __restrict__ outp)
{
  __shared__ __align__(16) __bf16 sh_h[2][BB * STR];          // h double buffer (17.4 KB)
  __shared__ __align__(16) unsigned short sh_sA[BB * 264];    // setup staging hi (16.9 KB)
  __shared__ __align__(16) unsigned short sh_sB[BB * 264];    // setup staging lo (16.9 KB)
  __shared__ __align__(16) uint4 sh_wof[4 * 64];              // Wo B-frags (4 KB)
  __shared__ float sh_pw0[8][BB * 2];     // setup pred partials (2 KB)
  __shared__ float sh_p0[BB * 2];         // virtual pred_{-1} for t=0 correction

  const int tid  = threadIdx.x;
  const int w    = tid >> 6;
  const int l    = tid & 63;
  const int q    = l >> 4;
  const int c16  = l & 15;
  const int colH = w * 16 + c16;
  const int rbase = blockIdx.x * BB;

  const float Lc = 1.4426950408889634f;          // log2(e)
  const float SG[4] = {Lc, Lc, 2.f * Lc, Lc};    // i, f, g, o exp2 prescales
  const float bo0 = bo[0], bo1 = bo[1];
  const float wo0 = Wo[colH], wo1 = Wo[HDIM + colH];

  // feedback weights per gate (W_prev columns)
  float wp0[4], wp1[4];
  #pragma unroll
  for (int g = 0; g < 4; ++g) {
    wp0[g] = W_ih[(size_t)(g * HDIM + colH) * 132 + 0];
    wp1[g] = W_ih[(size_t)(g * HDIM + colH) * 132 + 1];
  }

  // ---- persistent W_eff fragments: SG[g]*(W_hh + wp0*Wo0 + wp1*Wo1) ----
  frag_u Wf[4][4];                  // [gate][ktile]  (64 VGPRs)
  #pragma unroll
  for (int kt = 0; kt < 4; ++kt) {
    const float* w0p = Wo + kt * 32 + q * 8;
    const float* w1p = Wo + HDIM + kt * 32 + q * 8;
    float4 a0 = *(const float4*)w0p, a1 = *(const float4*)(w0p + 4);
    float4 b0 = *(const float4*)w1p, b1 = *(const float4*)(w1p + 4);
    float wo0v[8] = {a0.x, a0.y, a0.z, a0.w, a1.x, a1.y, a1.z, a1.w};
    float wo1v[8] = {b0.x, b0.y, b0.z, b0.w, b1.x, b1.y, b1.z, b1.w};
    #pragma unroll
    for (int g = 0; g < 4; ++g) {
      const float* wr = W_hh + (size_t)(g * HDIM + colH) * HDIM + kt * 32 + q * 8;
      float4 f0 = *(const float4*)wr;
      float4 f1 = *(const float4*)(wr + 4);
      float ff[8] = {f0.x, f0.y, f0.z, f0.w, f1.x, f1.y, f1.z, f1.w};
      #pragma unroll
      for (int j = 0; j < 8; ++j)
        Wf[g][kt].s[j] = f2bf(SG[g] * (ff[j] + wp0[g] * wo0v[j] + wp1[g] * wo1v[j]));
    }
  }

  // ---- Wo B-fragments for the pred MFMA -> LDS (waves 6/7 read) ----
  #pragma unroll
  for (int kt = 0; kt < 4; ++kt) {
    frag_u wf;
    #pragma unroll
    for (int j = 0; j < 8; ++j) {
      float x = (c16 < 2) ? Wo[c16 * HDIM + kt * 32 + q * 8 + j] : 0.f;
      wf.s[j] = f2bf(x);
    }
    if (w == 0) sh_wof[kt * 64 + l] = wf.u4;
  }

  // ---- stage context rows (32 rows, hi/lo bf16, stride 264) ----
  for (int e = tid; e < BB * 256; e += 512) {
    int row = e >> 8, col = e & 255;
    float x = ctx[(size_t)(rbase + row) * CTX_DIM + col];
    unsigned short hb = f2bf(x);
    sh_sA[row * 264 + col] = hb;
    sh_sB[row * 264 + col] = f2bf(x - bf2f(hb));
  }
  __syncthreads();

  // ---- h0/c0 = ctx @ Wh.T/Wc.T + bias (3-product split, K=256, 2 groups) ----
  float cst[2][4];   // [group][r]  (raw units)
  {
    f32x4 aH[2] = {{0.f,0.f,0.f,0.f},{0.f,0.f,0.f,0.f}};
    f32x4 aC[2] = {{0.f,0.f,0.f,0.f},{0.f,0.f,0.f,0.f}};
    #pragma unroll
    for (int kt = 0; kt < 8; ++kt) {
      frag_u Ahi[2], Alo[2];
      #pragma unroll
      for (int rt = 0; rt < 2; ++rt) {
        Ahi[rt].u4 = *(const uint4*)&sh_sA[(rt * 16 + c16) * 264 + kt * 32 + q * 8];
        Alo[rt].u4 = *(const uint4*)&sh_sB[(rt * 16 + c16) * 264 + kt * 32 + q * 8];
      }
      frag_u bhi, blo;
      {
        const float* wr = Wh + (size_t)colH * CTX_DIM + kt * 32 + q * 8;
        float4 f0 = *(const float4*)wr;
        float4 f1 = *(const float4*)(wr + 4);
        float ff[8] = {f0.x, f0.y, f0.z, f0.w, f1.x, f1.y, f1.z, f1.w};
        #pragma unroll
        for (int j = 0; j < 8; ++j) {
          unsigned short hb = f2bf(ff[j]);
          bhi.s[j] = hb;
          blo.s[j] = f2bf(ff[j] - bf2f(hb));
        }
      }
      #pragma unroll
      for (int rt = 0; rt < 2; ++rt) {
        aH[rt] = MFMA(Ahi[rt].v, bhi.v, aH[rt]);
        aH[rt] = MFMA(Alo[rt].v, bhi.v, aH[rt]);
        aH[rt] = MFMA(Ahi[rt].v, blo.v, aH[rt]);
      }
      {
        const float* wr = Wc + (size_t)colH * CTX_DIM + kt * 32 + q * 8;
        float4 f0 = *(const float4*)wr;
        float4 f1 = *(const float4*)(wr + 4);
        float ff[8] = {f0.x, f0.y, f0.z, f0.w, f1.x, f1.y, f1.z, f1.w};
        #pragma unroll
        for (int j = 0; j < 8; ++j) {
          unsigned short hb = f2bf(ff[j]);
          bhi.s[j] = hb;
          blo.s[j] = f2bf(ff[j] - bf2f(hb));
        }
      }
      #pragma unroll
      for (int rt = 0; rt < 2; ++rt) {
        aC[rt] = MFMA(Ahi[rt].v, bhi.v, aC[rt]);
        aC[rt] = MFMA(Alo[rt].v, bhi.v, aC[rt]);
        aC[rt] = MFMA(Ahi[rt].v, blo.v, aC[rt]);
      }
    }
    float bhv = bh[colH], bcv = bc[colH];
    float pp0[8][2];
    #pragma unroll
    for (int rt = 0; rt < 2; ++rt) {
      #pragma unroll
      for (int r = 0; r < 4; ++r) {
        float h0v = aH[rt][r] + bhv;
        cst[rt][r] = aC[rt][r] + bcv;
        sh_h[0][(rt * 16 + q * 4 + r) * STR + colH] = (__bf16)h0v;
        pp0[rt * 4 + r][0] = h0v * wo0;
        pp0[rt * 4 + r][1] = h0v * wo1;
      }
    }
    #pragma unroll
    for (int m = 0; m < 8; ++m) {
      pp0[m][0] = row_reduce16(pp0[m][0]);
      pp0[m][1] = row_reduce16(pp0[m][1]);
    }
    if (c16 == 0) {
      #pragma unroll
      for (int rt = 0; rt < 2; ++rt)
        #pragma unroll
        for (int r = 0; r < 4; ++r) {
          sh_pw0[w][(rt * 16 + q * 4 + r) * 2 + 0] = pp0[rt * 4 + r][0];
          sh_pw0[w][(rt * 16 + q * 4 + r) * 2 + 1] = pp0[rt * 4 + r][1];
        }
    }
  }
  __syncthreads();   // sA/sB reuse + pw0 visibility

  // ---- stage static_in = [ball(2), enc(128), pad] (32 rows, stride 168) ----
  for (int e = tid; e < BB * 168; e += 512) {
    int row = e / 168, col = e - row * 168;
    float x = (col < 2) ? ball[(size_t)(rbase + row) * 2 + col]
            : (col < 130) ? enc[(size_t)(rbase + row) * 128 + (col - 2)] : 0.f;
    unsigned short hb = f2bf(x);
    sh_sA[row * 168 + col] = hb;
    sh_sB[row * 168 + col] = f2bf(x - bf2f(hb));
  }
  // virtual pred_{-1} = h0 @ Wo.T + bo (t=0 feedback correction)
  if (tid < BB * 2) {
    float s = (tid & 1) ? bo1 : bo0;
    #pragma unroll
    for (int w2 = 0; w2 < 8; ++w2) s += sh_pw0[w2][tid];
    sh_p0[tid] = s;
  }
  __syncthreads();

  // ---- gate_static (3-product, K=160, SG-scaled) + biases, in REGISTERS ----
  f32x4 gacc[2][4] = {{{0.f,0.f,0.f,0.f},{0.f,0.f,0.f,0.f},{0.f,0.f,0.f,0.f},{0.f,0.f,0.f,0.f}},
                      {{0.f,0.f,0.f,0.f},{0.f,0.f,0.f,0.f},{0.f,0.f,0.f,0.f},{0.f,0.f,0.f,0.f}}};
  #pragma unroll
  for (int kt = 0; kt < 5; ++kt) {
    frag_u Ahi[2], Alo[2];
    #pragma unroll
    for (int rt = 0; rt < 2; ++rt) {
      Ahi[rt].u4 = *(const uint4*)&sh_sA[(rt * 16 + c16) * 168 + kt * 32 + q * 8];
      Alo[rt].u4 = *(const uint4*)&sh_sB[(rt * 16 + c16) * 168 + kt * 32 + q * 8];
    }
    #pragma unroll
    for (int g = 0; g < 4; ++g) {
      frag_u bhi, blo;
      #pragma unroll
      for (int j = 0; j < 8; ++j) {
        int kk = kt * 32 + q * 8 + j;
        float x = (kk < 130) ? SG[g] * W_ih[(size_t)(g * HDIM + colH) * 132 + 2 + kk] : 0.f;
        unsigned short hb = f2bf(x);
        bhi.s[j] = hb;
        blo.s[j] = f2bf(x - bf2f(hb));
      }
      #pragma unroll
      for (int rt = 0; rt < 2; ++rt) {
        gacc[rt][g] = MFMA(Ahi[rt].v, bhi.v, gacc[rt][g]);
        gacc[rt][g] = MFMA(Alo[rt].v, bhi.v, gacc[rt][g]);
        gacc[rt][g] = MFMA(Ahi[rt].v, blo.v, gacc[rt][g]);
      }
    }
  }
  // scaled feedback weights (t=0 correction operates in scaled units)
  float wps0[4], wps1[4];
  #pragma unroll
  for (int g = 0; g < 4; ++g) {
    int colG = g * HDIM + colH;
    float bb = SG[g] * (b_ih[colG] + b_hh[colG] + bo0 * wp0[g] + bo1 * wp1[g]);
    #pragma unroll
    for (int rt = 0; rt < 2; ++rt)
      #pragma unroll
      for (int r = 0; r < 4; ++r) gacc[rt][g][r] += bb;
    wps0[g] = SG[g] * wp0[g];
    wps1[g] = SG[g] * wp1[g];
  }

  // ---- phase-shifted time loop, anti-lockstep wave ordering ----
  // Phase(G,t): MFMA group G gates at time t (reads h_G(t) = buf[t&1] rows G);
  //             EW for group E=1-G consuming acc[E], writing h_E -> disjoint
  //             rows / other buffer. The two sections are data-independent:
  //             waves 0-3 run [MFMA; EW], waves 4-7 run [EW; MFMA] so each
  //             SIMD (w%4) always has one MFMA-issuing and one VALU-issuing
  //             wave. One barrier per phase.
  f32x4 acc[2][4];

  auto phase = [&](auto GC, int t, bool doEw, bool corr, bool doPred) {
    constexpr int G = decltype(GC)::value;
    constexpr int E = 1 - G;
    const int rbuf = t & 1;
    const __bf16* hp = &sh_h[rbuf][(G * 16 + c16) * STR];

    auto mfmaPart = [&]() {
      // --- MFMA gates for group G at time t (seeded by gate_static)
      frag_u A[4];
      #pragma unroll
      for (int kt = 0; kt < 4; ++kt)
        A[kt].u4 = *(const uint4*)(hp + kt * 32 + q * 8);
      #pragma unroll
      for (int g = 0; g < 4; ++g) acc[G][g] = gacc[G][g];
      #pragma unroll
      for (int kt = 0; kt < 4; ++kt)
        #pragma unroll
        for (int g = 0; g < 4; ++g)
          acc[G][g] = MFMA(A[kt].v, Wf[g][kt].v, acc[G][g]);

      // --- pred[t-1] rows G = h_G(t) @ Wo (wave 6 for A, wave 7 for B)
      if (doPred && w == 6 + G) {
        f32x4 accP = {0.f, 0.f, 0.f, 0.f};
        #pragma unroll
        for (int kt = 0; kt < 4; ++kt) {
          frag_u wof;
          wof.u4 = sh_wof[kt * 64 + l];
          accP = MFMA(A[kt].v, wof.v, accP);
        }
        if (c16 < 2) {
          const int m0 = G * 16 + q * 4;
          const float bov = c16 ? bo1 : bo0;
          #pragma unroll
          for (int r = 0; r < 4; ++r)
            outp[(size_t)(rbase + m0 + r) * (T_FRAMES * 2) + (t - 1) * 2 + c16] = accP[r] + bov;
        }
      }
    };

    auto ewPart = [&]() {
      // --- elementwise for group E (independent of this phase's MFMAs)
      if (doEw) {
        if (corr) {  // gates at tE==0: remove folded pred_{-1} feedback (scaled)
          #pragma unroll
          for (int r = 0; r < 4; ++r) {
            float2 p0r = *(const float2*)&sh_p0[(E * 16 + q * 4 + r) * 2];
            #pragma unroll
            for (int g = 0; g < 4; ++g)
              acc[E][g][r] -= p0r.x * wps0[g] + p0r.y * wps1[g];
          }
        }
        __bf16* hwp = &sh_h[(t + G) & 1][(E * 16) * STR + colH];
        #pragma unroll
        for (int r = 0; r < 4; ++r) {
          float ei = EXP2(-acc[E][0][r]);          // e^{-i}
          float ef = EXP2(-acc[E][1][r]);          // e^{-f}
          float eg = EXP2(-acc[E][2][r]);          // e^{-2g}
          float eo = EXP2(-acc[E][3][r]);          // e^{-o}
          float t1 = (1.f + ei) * (1.f + eg);
          float pf = 1.f + ef;
          float num = cst[E][r] * t1 + (1.f - eg) * pf;
          float cv = num * RCP(t1 * pf);
          cst[E][r] = cv;
          float cc = fmaxf(cv, -15.f);             // only -inf side can overflow
          float ec = EXP2(cc * (-2.f * 1.4426950408889634f));
          float hv = (1.f - ec) * RCP((1.f + eo) * (1.f + ec));
          hwp[(q * 4 + r) * STR] = (__bf16)hv;
        }
      }
    };

    if (w < 4) { mfmaPart(); ewPart(); }
    else       { ewPart(); mfmaPart(); }
    __syncthreads();
  };

  phase(Int<0>{}, 0, false, false, false);   // MFMA A(0)
  phase(Int<1>{}, 0, true,  true,  false);   // MFMA B(0); ew A(0)+corr -> h_A(1)
  phase(Int<0>{}, 1, true,  true,  true);    // MFMA A(1); ew B(0)+corr -> h_B(1); pred[0]A
  for (int t = 1; t < 127; ++t) {
    phase(Int<1>{}, t,     true, false, true);   // MFMA B(t);   ew A(t)   -> h_A(t+1); pred[t-1]B
    phase(Int<0>{}, t + 1, true, false, true);   // MFMA A(t+1); ew B(t)   -> h_B(t+1); pred[t]A
  }
  phase(Int<1>{}, 127, true, false, true);   // MFMA B(127); ew A(127) -> h_A(128); pred[126]B

  // final elementwise: B(127) -> h_B(128) into buf[0]
  {
    __bf16* hwp = &sh_h[0][16 * STR + colH];
    #pragma unroll
    for (int r = 0; r < 4; ++r) {
      float ei = EXP2(-acc[1][0][r]);
      float ef = EXP2(-acc[1][1][r]);
      float eg = EXP2(-acc[1][2][r]);
      float eo = EXP2(-acc[1][3][r]);
      float t1 = (1.f + ei) * (1.f + eg);
      float pf = 1.f + ef;
      float num = cst[1][r] * t1 + (1.f - eg) * pf;
      float cv = num * RCP(t1 * pf);
      float cc = fmaxf(cv, -15.f);
      float ec = EXP2(cc * (-2.f * 1.4426950408889634f));
      float hv = (1.f - ec) * RCP((1.f + eo) * (1.f + ec));
      hwp[(q * 4 + r) * STR] = (__bf16)hv;
    }
  }
  __syncthreads();

  // ---- epilogue: pred[127] from h(128) (buf 0), waves 6 (A) / 7 (B) ----
  if (w == 6 || w == 7) {
    const int Ge = w - 6;
    const __bf16* hp = &sh_h[0][(Ge * 16 + c16) * STR];
    f32x4 accP = {0.f, 0.f, 0.f, 0.f};
    #pragma unroll
    for (int kt = 0; kt < 4; ++kt) {
      frag_u A, wof;
      A.u4 = *(const uint4*)(hp + kt * 32 + q * 8);
      wof.u4 = sh_wof[kt * 64 + l];
      accP = MFMA(A.v, wof.v, accP);
    }
    if (c16 < 2) {
      const int m0 = Ge * 16 + q * 4;
      const float bov = c16 ? bo1 : bo0;
      #pragma unroll
      for (int r = 0; r < 4; ++r)
        outp[(size_t)(rbase + m0 + r) * (T_FRAMES * 2) + 127 * 2 + c16] = accP[r] + bov;
    }
  }
}

extern "C" void kernel_launch(void* const* d_in, const int* in_sizes, int n_in,
                              void* d_out, int out_size, void* d_ws, size_t ws_size,
                              hipStream_t stream) {
  (void)in_sizes; (void)n_in; (void)d_ws; (void)ws_size; (void)out_size;
  const float* ctx  = (const float*)d_in[0];
  const float* enc  = (const float*)d_in[1];
  const float* ball = (const float*)d_in[2];
  // d_in[3] = max_frames (always 128)
  const float* Wh   = (const float*)d_in[4];
  const float* bh   = (const float*)d_in[5];
  const float* Wc   = (const float*)d_in[6];
  const float* bc   = (const float*)d_in[7];
  const float* W_ih = (const float*)d_in[8];
  const float* W_hh = (const float*)d_in[9];
  const float* b_ih = (const float*)d_in[10];
  const float* b_hh = (const float*)d_in[11];
  const float* Wo   = (const float*)d_in[12];
  const float* bo   = (const float*)d_in[13];
  float* outp = (float*)d_out;

  dim3 grid(256), block(512);
  traj_lstm<<<grid, block, 0, stream>>>(ctx, enc, ball, Wh, bh, Wc, bc,
                                        W_ih, W_hh, b_ih, b_hh, Wo, bo, outp);
}

// Round 7
// 312.559 us; speedup vs baseline: 1.5329x; 1.1053x over previous
//
#include <hip/hip_runtime.h>
#include <hip/hip_bf16.h>

// TrajectoryDecoder: B=8192 LSTM, T=128, H=128, CTX=256, IN_DIM=132.
// R17: two independent barrier domains per CU, zero spill risk.
// R16 failed to compile ("+a" tied asm on uint4 unsupported). Mechanism
// review: R12 proved per-lane Wf = Wf_total/lanes; R13/R15 proved no
// within-domain overlap; R11/R14 proved >128-reg-demand at high occupancy
// spills. The untested cell: 2 blocks/CU with per-wave demand that FITS.
// Transpose R10's wave shape (1 col-tile x 2 row-tiles) to
// (2 col-tiles x 1 row-tile): BB=16 needs only 4 waves -> 256-thr blocks,
// 512 blocks, 2 per CU. Per-SIMD: still 2 waves, but from DIFFERENT
// barrier domains -> block A's barrier/dep stalls (~45% in R10) are filled
// by block B's issue (m114). Register budget: launch_bounds(256,2) = 256
// regs; demand ~= Wf 128 + acc 32 + A 16 + cst 8 + temps ~35 ~= 220. Seeds
// (gate_static) in lane-private LDS f32x4 slots (conflict-free b128).
// t=0 pred_{-1} correction folded into seeds, unfolded after body(0) ->
// uniform loop body. LDS ~64KB/block x2 = 127KB < 160. Elementwise math
// unchanged (exp2 prescale SG={L,L,2L,L}, 7 trans/elem).

#define HDIM 128
#define CTX_DIM 256
#define T_FRAMES 128
#define BB 16     // batch rows per block (512 blocks, 2 per CU)
#define STR 136   // h row stride (elements); 272B rows keep 16B alignment

typedef __bf16 bf16x8 __attribute__((ext_vector_type(8)));
typedef float  f32x4  __attribute__((ext_vector_type(4)));

union frag_u {
  bf16x8 v;
  unsigned short s[8];
  uint4 u4;
};

#if __has_builtin(__builtin_amdgcn_exp2f)
#define EXP2(x) __builtin_amdgcn_exp2f(x)
#else
#define EXP2(x) __expf((x) * 0.6931471805599453f)
#endif
#define RCP(x) __builtin_amdgcn_rcpf(x)

__device__ __forceinline__ unsigned short f2bf(float x) {
  unsigned u = __builtin_bit_cast(unsigned, x);
  u += 0x7FFFu + ((u >> 16) & 1u);          // RNE to bf16
  return (unsigned short)(u >> 16);
}
__device__ __forceinline__ float bf2f(unsigned short h) {
  unsigned u = ((unsigned)h) << 16;
  return __builtin_bit_cast(float, u);
}
template<int CTRL>
__device__ __forceinline__ float dpp_mov(float x) {
  return __builtin_bit_cast(float,
    __builtin_amdgcn_mov_dpp(__builtin_bit_cast(int, x), CTRL, 0xF, 0xF, true));
}
// sum over the 16-lane row group (setup-only)
__device__ __forceinline__ float row_reduce16(float v) {
  v += dpp_mov<0xB1>(v);     // quad_perm xor1
  v += dpp_mov<0x4E>(v);     // quad_perm xor2
  v += dpp_mov<0x124>(v);    // row_ror:4
  v += dpp_mov<0x128>(v);    // row_ror:8
  return v;
}

#define MFMA(a, b, c) __builtin_amdgcn_mfma_f32_16x16x32_bf16((a), (b), (c), 0, 0, 0)

__global__ __launch_bounds__(256, 2) void traj_lstm(
    const float* __restrict__ ctx, const float* __restrict__ enc,
    const float* __restrict__ ball,
    const float* __restrict__ Wh, const float* __restrict__ bh,
    const float* __restrict__ Wc, const float* __restrict__ bc,
    const float* __restrict__ W_ih, const float* __restrict__ W_hh,
    const float* __restrict__ b_ih, const float* __restrict__ b_hh,
    const float* __restrict__ Wo, const float* __restrict__ bo,
    float* __restrict__ outp)
{
  __shared__ __align__(16) __bf16 sh_h[2][BB * STR];          // h double buffer (8.7 KB)
  __shared__ __align__(16) unsigned short sh_sA[BB * 264];    // setup staging hi (8.4 KB)
  __shared__ __align__(16) unsigned short sh_sB[BB * 264];    // setup staging lo (8.4 KB)
  __shared__ __align__(16) f32x4 sh_gs[8 * 4 * 64];           // C-seeds, lane-private slots (32 KB)
  __shared__ __align__(16) uint4 sh_wof[4 * 64];              // Wo B-frags (4 KB)
  __shared__ float sh_pw0[4][BB * 2];     // setup pred partials (0.5 KB)
  __shared__ float sh_p0[BB * 2];         // virtual pred_{-1} for t=0 correction

  const int tid  = threadIdx.x;
  const int w    = tid >> 6;          // 0..3
  const int l    = tid & 63;
  const int q    = l >> 4;
  const int c16  = l & 15;
  const int rbase = blockIdx.x * BB;
  const int colC[2] = { w * 32 + c16, w * 32 + 16 + c16 };

  const float Lc = 1.4426950408889634f;          // log2(e)
  const float SG[4] = {Lc, Lc, 2.f * Lc, Lc};    // i, f, g, o exp2 prescales
  const float bo0 = bo[0], bo1 = bo[1];

  // ---- Wo B-fragments for the pred MFMA -> LDS (wave 0 reads in-loop) ----
  #pragma unroll
  for (int kt = 0; kt < 4; ++kt) {
    frag_u wf;
    #pragma unroll
    for (int j = 0; j < 8; ++j) {
      float x = (c16 < 2) ? Wo[c16 * HDIM + kt * 32 + q * 8 + j] : 0.f;
      wf.s[j] = f2bf(x);
    }
    if (w == 0) sh_wof[kt * 64 + l] = wf.u4;
  }

  // ---- stage context rows (16 rows, hi/lo bf16, stride 264) ----
  for (int e = tid; e < BB * 256; e += 256) {
    int row = e >> 8, col = e & 255;
    float x = ctx[(size_t)(rbase + row) * CTX_DIM + col];
    unsigned short hb = f2bf(x);
    sh_sA[row * 264 + col] = hb;
    sh_sB[row * 264 + col] = f2bf(x - bf2f(hb));
  }
  __syncthreads();

  // ---- h0/c0 = ctx @ Wh.T/Wc.T + bias (3-product split, K=256, 2 col-tiles) ----
  float cst[2][4];   // [ctl][r]  (raw units)
  {
    f32x4 aH[2] = {{0.f,0.f,0.f,0.f},{0.f,0.f,0.f,0.f}};
    f32x4 aC[2] = {{0.f,0.f,0.f,0.f},{0.f,0.f,0.f,0.f}};
    #pragma unroll
    for (int kt = 0; kt < 8; ++kt) {
      frag_u Ahi, Alo;
      Ahi.u4 = *(const uint4*)&sh_sA[c16 * 264 + kt * 32 + q * 8];
      Alo.u4 = *(const uint4*)&sh_sB[c16 * 264 + kt * 32 + q * 8];
      #pragma unroll
      for (int ctl = 0; ctl < 2; ++ctl) {
        frag_u bhi, blo;
        {
          const float* wr = Wh + (size_t)colC[ctl] * CTX_DIM + kt * 32 + q * 8;
          float4 f0 = *(const float4*)wr;
          float4 f1 = *(const float4*)(wr + 4);
          float ff[8] = {f0.x, f0.y, f0.z, f0.w, f1.x, f1.y, f1.z, f1.w};
          #pragma unroll
          for (int j = 0; j < 8; ++j) {
            unsigned short hb = f2bf(ff[j]);
            bhi.s[j] = hb;
            blo.s[j] = f2bf(ff[j] - bf2f(hb));
          }
        }
        aH[ctl] = MFMA(Ahi.v, bhi.v, aH[ctl]);
        aH[ctl] = MFMA(Alo.v, bhi.v, aH[ctl]);
        aH[ctl] = MFMA(Ahi.v, blo.v, aH[ctl]);
        {
          const float* wr = Wc + (size_t)colC[ctl] * CTX_DIM + kt * 32 + q * 8;
          float4 f0 = *(const float4*)wr;
          float4 f1 = *(const float4*)(wr + 4);
          float ff[8] = {f0.x, f0.y, f0.z, f0.w, f1.x, f1.y, f1.z, f1.w};
          #pragma unroll
          for (int j = 0; j < 8; ++j) {
            unsigned short hb = f2bf(ff[j]);
            bhi.s[j] = hb;
            blo.s[j] = f2bf(ff[j] - bf2f(hb));
          }
        }
        aC[ctl] = MFMA(Ahi.v, bhi.v, aC[ctl]);
        aC[ctl] = MFMA(Alo.v, bhi.v, aC[ctl]);
        aC[ctl] = MFMA(Ahi.v, blo.v, aC[ctl]);
      }
    }
    float pp0[4][2] = {{0.f,0.f},{0.f,0.f},{0.f,0.f},{0.f,0.f}};
    #pragma unroll
    for (int ctl = 0; ctl < 2; ++ctl) {
      float bhv = bh[colC[ctl]], bcv = bc[colC[ctl]];
      float wo0c = Wo[colC[ctl]], wo1c = Wo[HDIM + colC[ctl]];
      #pragma unroll
      for (int r = 0; r < 4; ++r) {
        float h0v = aH[ctl][r] + bhv;
        cst[ctl][r] = aC[ctl][r] + bcv;
        sh_h[0][(q * 4 + r) * STR + colC[ctl]] = (__bf16)h0v;
        pp0[r][0] += h0v * wo0c;
        pp0[r][1] += h0v * wo1c;
      }
    }
    #pragma unroll
    for (int m = 0; m < 4; ++m) {
      pp0[m][0] = row_reduce16(pp0[m][0]);
      pp0[m][1] = row_reduce16(pp0[m][1]);
    }
    if (c16 == 0) {
      #pragma unroll
      for (int r = 0; r < 4; ++r) {
        sh_pw0[w][(q * 4 + r) * 2 + 0] = pp0[r][0];
        sh_pw0[w][(q * 4 + r) * 2 + 1] = pp0[r][1];
      }
    }
  }
  __syncthreads();   // sA/sB reuse + pw0 visibility

  // ---- stage static_in = [ball(2), enc(128), pad] (16 rows, stride 168) ----
  for (int e = tid; e < BB * 168; e += 256) {
    int row = e / 168, col = e - row * 168;
    float x = (col < 2) ? ball[(size_t)(rbase + row) * 2 + col]
            : (col < 130) ? enc[(size_t)(rbase + row) * 128 + (col - 2)] : 0.f;
    unsigned short hb = f2bf(x);
    sh_sA[row * 168 + col] = hb;
    sh_sB[row * 168 + col] = f2bf(x - bf2f(hb));
  }
  // virtual pred_{-1} = h0 @ Wo.T + bo (t=0 feedback correction)
  if (tid < BB * 2) {
    float s = (tid & 1) ? bo1 : bo0;
    #pragma unroll
    for (int w2 = 0; w2 < 4; ++w2) s += sh_pw0[w2][tid];
    sh_p0[tid] = s;
  }
  __syncthreads();

  // ---- gate_static (3-product, K=160, SG-scaled) -> lane-private LDS seeds ----
  {
    f32x4 gacc[2][4] = {{{0.f,0.f,0.f,0.f},{0.f,0.f,0.f,0.f},{0.f,0.f,0.f,0.f},{0.f,0.f,0.f,0.f}},
                        {{0.f,0.f,0.f,0.f},{0.f,0.f,0.f,0.f},{0.f,0.f,0.f,0.f},{0.f,0.f,0.f,0.f}}};
    #pragma unroll
    for (int kt = 0; kt < 5; ++kt) {
      frag_u Ahi, Alo;
      Ahi.u4 = *(const uint4*)&sh_sA[c16 * 168 + kt * 32 + q * 8];
      Alo.u4 = *(const uint4*)&sh_sB[c16 * 168 + kt * 32 + q * 8];
      #pragma unroll
      for (int ctl = 0; ctl < 2; ++ctl) {
        #pragma unroll
        for (int g = 0; g < 4; ++g) {
          frag_u bhi, blo;
          #pragma unroll
          for (int j = 0; j < 8; ++j) {
            int kk = kt * 32 + q * 8 + j;
            float x = (kk < 130) ? SG[g] * W_ih[(size_t)(g * HDIM + colC[ctl]) * 132 + 2 + kk] : 0.f;
            unsigned short hb = f2bf(x);
            bhi.s[j] = hb;
            blo.s[j] = f2bf(x - bf2f(hb));
          }
          gacc[ctl][g] = MFMA(Ahi.v, bhi.v, gacc[ctl][g]);
          gacc[ctl][g] = MFMA(Alo.v, bhi.v, gacc[ctl][g]);
          gacc[ctl][g] = MFMA(Ahi.v, blo.v, gacc[ctl][g]);
        }
      }
    }
    // biases + FOLD t=0 correction into the seeds (lane-private slots)
    #pragma unroll
    for (int ctl = 0; ctl < 2; ++ctl) {
      #pragma unroll
      for (int g = 0; g < 4; ++g) {
        int colG = g * HDIM + colC[ctl];
        float wp0v = W_ih[(size_t)colG * 132 + 0];
        float wp1v = W_ih[(size_t)colG * 132 + 1];
        float bb = SG[g] * (b_ih[colG] + b_hh[colG] + bo0 * wp0v + bo1 * wp1v);
        f32x4 s = gacc[ctl][g];
        #pragma unroll
        for (int r = 0; r < 4; ++r) {
          float2 p0r = *(const float2*)&sh_p0[(q * 4 + r) * 2];
          s[r] += bb - SG[g] * (p0r.x * wp0v + p0r.y * wp1v);
        }
        sh_gs[((w * 2 + ctl) * 4 + g) * 64 + l] = s;
      }
    }
  }

  // ---- persistent W_eff fragments: SG[g]*(W_hh + wp0*Wo0 + wp1*Wo1) ----
  frag_u Wf[4][2][4];               // [gate][ctl][ktile]  (128 VGPRs)
  #pragma unroll
  for (int ctl = 0; ctl < 2; ++ctl) {
    #pragma unroll
    for (int kt = 0; kt < 4; ++kt) {
      const float* w0p = Wo + kt * 32 + q * 8;
      const float* w1p = Wo + HDIM + kt * 32 + q * 8;
      float4 a0 = *(const float4*)w0p, a1 = *(const float4*)(w0p + 4);
      float4 b0 = *(const float4*)w1p, b1 = *(const float4*)(w1p + 4);
      float wo0v[8] = {a0.x, a0.y, a0.z, a0.w, a1.x, a1.y, a1.z, a1.w};
      float wo1v[8] = {b0.x, b0.y, b0.z, b0.w, b1.x, b1.y, b1.z, b1.w};
      #pragma unroll
      for (int g = 0; g < 4; ++g) {
        int colG = g * HDIM + colC[ctl];
        float wp0v = W_ih[(size_t)colG * 132 + 0];
        float wp1v = W_ih[(size_t)colG * 132 + 1];
        const float* wr = W_hh + (size_t)colG * HDIM + kt * 32 + q * 8;
        float4 f0 = *(const float4*)wr;
        float4 f1 = *(const float4*)(wr + 4);
        float ff[8] = {f0.x, f0.y, f0.z, f0.w, f1.x, f1.y, f1.z, f1.w};
        #pragma unroll
        for (int j = 0; j < 8; ++j)
          Wf[g][ctl][kt].s[j] = f2bf(SG[g] * (ff[j] + wp0v * wo0v[j] + wp1v * wo1v[j]));
      }
    }
  }
  __syncthreads();

  // ---- uniform time loop: ONE barrier per step ----
  auto body = [&](int t, bool doPred) {
    const int rbuf = t & 1, wbuf = rbuf ^ 1;
    const __bf16* hp = &sh_h[rbuf][c16 * STR];

    frag_u A[4];
    #pragma unroll
    for (int kt = 0; kt < 4; ++kt)
      A[kt].u4 = *(const uint4*)(hp + kt * 32 + q * 8);

    f32x4 acc[2][4];
    #pragma unroll
    for (int ctl = 0; ctl < 2; ++ctl)
      #pragma unroll
      for (int g = 0; g < 4; ++g)
        acc[ctl][g] = sh_gs[((w * 2 + ctl) * 4 + g) * 64 + l];
    #pragma unroll
    for (int kt = 0; kt < 4; ++kt)
      #pragma unroll
      for (int g = 0; g < 4; ++g)
        #pragma unroll
        for (int ctl = 0; ctl < 2; ++ctl)
          acc[ctl][g] = MFMA(A[kt].v, Wf[g][ctl][kt].v, acc[ctl][g]);

    // pred[t-1] = h(t) @ Wo.T + bo (wave 0; rows 0-15, n=c16<2)
    if (doPred && w == 0) {
      f32x4 accP = {0.f, 0.f, 0.f, 0.f};
      #pragma unroll
      for (int kt = 0; kt < 4; ++kt) {
        frag_u wof;
        wof.u4 = sh_wof[kt * 64 + l];
        accP = MFMA(A[kt].v, wof.v, accP);
      }
      if (c16 < 2) {
        const float bov = c16 ? bo1 : bo0;
        #pragma unroll
        for (int r = 0; r < 4; ++r)
          outp[(size_t)(rbase + q * 4 + r) * (T_FRAMES * 2) + (t - 1) * 2 + c16] = accP[r] + bov;
      }
    }

    // elementwise update: 7 trans/element, exp2-prescaled gates
    #pragma unroll
    for (int ctl = 0; ctl < 2; ++ctl) {
      __bf16* hw = &sh_h[wbuf][colC[ctl]];
      #pragma unroll
      for (int r = 0; r < 4; ++r) {
        float ei = EXP2(-acc[ctl][0][r]);          // e^{-i}
        float ef = EXP2(-acc[ctl][1][r]);          // e^{-f}
        float eg = EXP2(-acc[ctl][2][r]);          // e^{-2g}
        float eo = EXP2(-acc[ctl][3][r]);          // e^{-o}
        float t1 = (1.f + ei) * (1.f + eg);
        float pf = 1.f + ef;
        float num = cst[ctl][r] * t1 + (1.f - eg) * pf;
        float cv = num * RCP(t1 * pf);
        cst[ctl][r] = cv;
        float cc = fmaxf(cv, -15.f);               // only -inf side can overflow
        float ec = EXP2(cc * (-2.f * 1.4426950408889634f));
        float hv = (1.f - ec) * RCP((1.f + eo) * (1.f + ec));
        hw[(q * 4 + r) * STR] = (__bf16)hv;
      }
    }
    __syncthreads();
  };

  body(0, false);   // seeds carry the folded t=0 correction

  // un-fold the correction: seeds become the plain gate_static (lane-private)
  #pragma unroll
  for (int ctl = 0; ctl < 2; ++ctl) {
    #pragma unroll
    for (int g = 0; g < 4; ++g) {
      int colG = g * HDIM + colC[ctl];
      float wp0v = W_ih[(size_t)colG * 132 + 0];
      float wp1v = W_ih[(size_t)colG * 132 + 1];
      f32x4 s = sh_gs[((w * 2 + ctl) * 4 + g) * 64 + l];
      #pragma unroll
      for (int r = 0; r < 4; ++r) {
        float2 p0r = *(const float2*)&sh_p0[(q * 4 + r) * 2];
        s[r] += SG[g] * (p0r.x * wp0v + p0r.y * wp1v);
      }
      sh_gs[((w * 2 + ctl) * 4 + g) * 64 + l] = s;
    }
  }
  __syncthreads();

  for (int t = 1; t < 128; ++t)
    body(t, true);   // body(127) stores pred[126]; h_128 -> buf 0

  // ---- epilogue: pred[127] from final h (buf 0), wave 0 ----
  if (w == 0) {
    const __bf16* hp = &sh_h[0][c16 * STR];
    f32x4 accP = {0.f, 0.f, 0.f, 0.f};
    #pragma unroll
    for (int kt = 0; kt < 4; ++kt) {
      frag_u A, wof;
      A.u4 = *(const uint4*)(hp + kt * 32 + q * 8);
      wof.u4 = sh_wof[kt * 64 + l];
      accP = MFMA(A.v, wof.v, accP);
    }
    if (c16 < 2) {
      const float bov = c16 ? bo1 : bo0;
      #pragma unroll
      for (int r = 0; r < 4; ++r)
        outp[(size_t)(rbase + q * 4 + r) * (T_FRAMES * 2) + 127 * 2 + c16] = accP[r] + bov;
    }
  }
}

extern "C" void kernel_launch(void* const* d_in, const int* in_sizes, int n_in,
                              void* d_out, int out_size, void* d_ws, size_t ws_size,
                              hipStream_t stream) {
  (void)in_sizes; (void)n_in; (void)d_ws; (void)ws_size; (void)out_size;
  const float* ctx  = (const float*)d_in[0];
  const float* enc  = (const float*)d_in[1];
  const float* ball = (const float*)d_in[2];
  // d_in[3] = max_frames (always 128)
  const float* Wh   = (const float*)d_in[4];
  const float* bh   = (const float*)d_in[5];
  const float* Wc   = (const float*)d_in[6];
  const float* bc   = (const float*)d_in[7];
  const float* W_ih = (const float*)d_in[8];
  const float* W_hh = (const float*)d_in[9];
  const float* b_ih = (const float*)d_in[10];
  const float* b_hh = (const float*)d_in[11];
  const float* Wo   = (const float*)d_in[12];
  const float* bo   = (const float*)d_in[13];
  float* outp = (float*)d_out;

  dim3 grid(512), block(256);
  traj_lstm<<<grid, block, 0, stream>>>(ctx, enc, ball, Wh, bh, Wc, bc,
                                        W_ih, W_hh, b_ih, b_hh, Wo, bo, outp);
}

// Round 8
// 312.412 us; speedup vs baseline: 1.5337x; 1.0005x over previous
//
#include <hip/hip_runtime.h>
#include <hip/hip_bf16.h>

// TrajectoryDecoder: B=8192 LSTM, T=128, H=128, CTX=256, IN_DIM=132.
// R18 = R13 (best, 260us) + pred stores -> LDS (bulk global write at end).
// Cross-round invariance (R10/R13/R17 all ~260-270us, VALU ~50, MFMA ~24
// regardless of occupancy/domain structure) pointed away from scheduling
// and at a per-phase serializer. Found it: __syncthreads emits
// s_waitcnt vmcnt(0) before s_barrier (m97 asm). R13's waves 6/7 issue
// 4 global_store_dword for pred[t-1] INSIDE every phase -> they drain
// stores to L2/HBM (~200-400cy) at every barrier, and being last to
// arrive, all 8 waves inherit it: ~255 phases x ~300cy ~= 36us of idle
// invisible to busy counters. Fix: pred[t] accumulates in a 32KB LDS
// buffer; one coalesced float4 bulk write after the loop. No other
// change vs R13 (attribution-clean).
// Keeps R13 structure: 512 thr, 1 block/CU, launch_bounds(512,1),
// phase-shifted A/B row groups, one barrier/phase, reg gate_static,
// exp2-prescaled gates SG={L,L,2L,L}, 7 trans/elem, t=0 corr.

#define HDIM 128
#define CTX_DIM 256
#define T_FRAMES 128
#define BB 32     // batch rows per block
#define STR 136   // h row stride (elements); 272B rows keep 16B alignment

typedef __bf16 bf16x8 __attribute__((ext_vector_type(8)));
typedef float  f32x4  __attribute__((ext_vector_type(4)));

union frag_u {
  bf16x8 v;
  unsigned short s[8];
  uint4 u4;
};

#if __has_builtin(__builtin_amdgcn_exp2f)
#define EXP2(x) __builtin_amdgcn_exp2f(x)
#else
#define EXP2(x) __expf((x) * 0.6931471805599453f)
#endif
#define RCP(x) __builtin_amdgcn_rcpf(x)

__device__ __forceinline__ unsigned short f2bf(float x) {
  unsigned u = __builtin_bit_cast(unsigned, x);
  u += 0x7FFFu + ((u >> 16) & 1u);          // RNE to bf16
  return (unsigned short)(u >> 16);
}
__device__ __forceinline__ float bf2f(unsigned short h) {
  unsigned u = ((unsigned)h) << 16;
  return __builtin_bit_cast(float, u);
}
template<int CTRL>
__device__ __forceinline__ float dpp_mov(float x) {
  return __builtin_bit_cast(float,
    __builtin_amdgcn_mov_dpp(__builtin_bit_cast(int, x), CTRL, 0xF, 0xF, true));
}
// sum over the 16-lane row group (setup-only)
__device__ __forceinline__ float row_reduce16(float v) {
  v += dpp_mov<0xB1>(v);     // quad_perm xor1
  v += dpp_mov<0x4E>(v);     // quad_perm xor2
  v += dpp_mov<0x124>(v);    // row_ror:4
  v += dpp_mov<0x128>(v);    // row_ror:8
  return v;
}

template<int N> struct Int { static constexpr int value = N; };

#define MFMA(a, b, c) __builtin_amdgcn_mfma_f32_16x16x32_bf16((a), (b), (c), 0, 0, 0)

__global__ __launch_bounds__(512, 1) void traj_lstm(
    const float* __restrict__ ctx, const float* __restrict__ enc,
    const float* __restrict__ ball,
    const float* __restrict__ Wh, const float* __restrict__ bh,
    const float* __restrict__ Wc, const float* __restrict__ bc,
    const float* __restrict__ W_ih, const float* __restrict__ W_hh,
    const float* __restrict__ b_ih, const float* __restrict__ b_hh,
    const float* __restrict__ Wo, const float* __restrict__ bo,
    float* __restrict__ outp)
{
  __shared__ __align__(16) __bf16 sh_h[2][BB * STR];          // h double buffer (17.4 KB)
  __shared__ __align__(16) unsigned short sh_sA[BB * 264];    // setup staging hi (16.9 KB)
  __shared__ __align__(16) unsigned short sh_sB[BB * 264];    // setup staging lo (16.9 KB)
  __shared__ __align__(16) uint4 sh_wof[4 * 64];              // Wo B-frags (4 KB)
  __shared__ __align__(16) float sh_pred[BB * 256];           // pred accumulation (32 KB)
  __shared__ float sh_pw0[8][BB * 2];     // setup pred partials (2 KB)
  __shared__ float sh_p0[BB * 2];         // virtual pred_{-1} for t=0 correction

  const int tid  = threadIdx.x;
  const int w    = tid >> 6;
  const int l    = tid & 63;
  const int q    = l >> 4;
  const int c16  = l & 15;
  const int colH = w * 16 + c16;
  const int rbase = blockIdx.x * BB;

  const float Lc = 1.4426950408889634f;          // log2(e)
  const float SG[4] = {Lc, Lc, 2.f * Lc, Lc};    // i, f, g, o exp2 prescales
  const float bo0 = bo[0], bo1 = bo[1];
  const float wo0 = Wo[colH], wo1 = Wo[HDIM + colH];

  // feedback weights per gate (W_prev columns)
  float wp0[4], wp1[4];
  #pragma unroll
  for (int g = 0; g < 4; ++g) {
    wp0[g] = W_ih[(size_t)(g * HDIM + colH) * 132 + 0];
    wp1[g] = W_ih[(size_t)(g * HDIM + colH) * 132 + 1];
  }

  // ---- persistent W_eff fragments: SG[g]*(W_hh + wp0*Wo0 + wp1*Wo1) ----
  frag_u Wf[4][4];                  // [gate][ktile]  (64 VGPRs)
  #pragma unroll
  for (int kt = 0; kt < 4; ++kt) {
    const float* w0p = Wo + kt * 32 + q * 8;
    const float* w1p = Wo + HDIM + kt * 32 + q * 8;
    float4 a0 = *(const float4*)w0p, a1 = *(const float4*)(w0p + 4);
    float4 b0 = *(const float4*)w1p, b1 = *(const float4*)(w1p + 4);
    float wo0v[8] = {a0.x, a0.y, a0.z, a0.w, a1.x, a1.y, a1.z, a1.w};
    float wo1v[8] = {b0.x, b0.y, b0.z, b0.w, b1.x, b1.y, b1.z, b1.w};
    #pragma unroll
    for (int g = 0; g < 4; ++g) {
      const float* wr = W_hh + (size_t)(g * HDIM + colH) * HDIM + kt * 32 + q * 8;
      float4 f0 = *(const float4*)wr;
      float4 f1 = *(const float4*)(wr + 4);
      float ff[8] = {f0.x, f0.y, f0.z, f0.w, f1.x, f1.y, f1.z, f1.w};
      #pragma unroll
      for (int j = 0; j < 8; ++j)
        Wf[g][kt].s[j] = f2bf(SG[g] * (ff[j] + wp0[g] * wo0v[j] + wp1[g] * wo1v[j]));
    }
  }

  // ---- Wo B-fragments for the pred MFMA -> LDS (waves 6/7 read) ----
  #pragma unroll
  for (int kt = 0; kt < 4; ++kt) {
    frag_u wf;
    #pragma unroll
    for (int j = 0; j < 8; ++j) {
      float x = (c16 < 2) ? Wo[c16 * HDIM + kt * 32 + q * 8 + j] : 0.f;
      wf.s[j] = f2bf(x);
    }
    if (w == 0) sh_wof[kt * 64 + l] = wf.u4;
  }

  // ---- stage context rows (32 rows, hi/lo bf16, stride 264) ----
  for (int e = tid; e < BB * 256; e += 512) {
    int row = e >> 8, col = e & 255;
    float x = ctx[(size_t)(rbase + row) * CTX_DIM + col];
    unsigned short hb = f2bf(x);
    sh_sA[row * 264 + col] = hb;
    sh_sB[row * 264 + col] = f2bf(x - bf2f(hb));
  }
  __syncthreads();

  // ---- h0/c0 = ctx @ Wh.T/Wc.T + bias (3-product split, K=256, 2 groups) ----
  float cst[2][4];   // [group][r]  (raw units)
  {
    f32x4 aH[2] = {{0.f,0.f,0.f,0.f},{0.f,0.f,0.f,0.f}};
    f32x4 aC[2] = {{0.f,0.f,0.f,0.f},{0.f,0.f,0.f,0.f}};
    #pragma unroll
    for (int kt = 0; kt < 8; ++kt) {
      frag_u Ahi[2], Alo[2];
      #pragma unroll
      for (int rt = 0; rt < 2; ++rt) {
        Ahi[rt].u4 = *(const uint4*)&sh_sA[(rt * 16 + c16) * 264 + kt * 32 + q * 8];
        Alo[rt].u4 = *(const uint4*)&sh_sB[(rt * 16 + c16) * 264 + kt * 32 + q * 8];
      }
      frag_u bhi, blo;
      {
        const float* wr = Wh + (size_t)colH * CTX_DIM + kt * 32 + q * 8;
        float4 f0 = *(const float4*)wr;
        float4 f1 = *(const float4*)(wr + 4);
        float ff[8] = {f0.x, f0.y, f0.z, f0.w, f1.x, f1.y, f1.z, f1.w};
        #pragma unroll
        for (int j = 0; j < 8; ++j) {
          unsigned short hb = f2bf(ff[j]);
          bhi.s[j] = hb;
          blo.s[j] = f2bf(ff[j] - bf2f(hb));
        }
      }
      #pragma unroll
      for (int rt = 0; rt < 2; ++rt) {
        aH[rt] = MFMA(Ahi[rt].v, bhi.v, aH[rt]);
        aH[rt] = MFMA(Alo[rt].v, bhi.v, aH[rt]);
        aH[rt] = MFMA(Ahi[rt].v, blo.v, aH[rt]);
      }
      {
        const float* wr = Wc + (size_t)colH * CTX_DIM + kt * 32 + q * 8;
        float4 f0 = *(const float4*)wr;
        float4 f1 = *(const float4*)(wr + 4);
        float ff[8] = {f0.x, f0.y, f0.z, f0.w, f1.x, f1.y, f1.z, f1.w};
        #pragma unroll
        for (int j = 0; j < 8; ++j) {
          unsigned short hb = f2bf(ff[j]);
          bhi.s[j] = hb;
          blo.s[j] = f2bf(ff[j] - bf2f(hb));
        }
      }
      #pragma unroll
      for (int rt = 0; rt < 2; ++rt) {
        aC[rt] = MFMA(Ahi[rt].v, bhi.v, aC[rt]);
        aC[rt] = MFMA(Alo[rt].v, bhi.v, aC[rt]);
        aC[rt] = MFMA(Ahi[rt].v, blo.v, aC[rt]);
      }
    }
    float bhv = bh[colH], bcv = bc[colH];
    float pp0[8][2];
    #pragma unroll
    for (int rt = 0; rt < 2; ++rt) {
      #pragma unroll
      for (int r = 0; r < 4; ++r) {
        float h0v = aH[rt][r] + bhv;
        cst[rt][r] = aC[rt][r] + bcv;
        sh_h[0][(rt * 16 + q * 4 + r) * STR + colH] = (__bf16)h0v;
        pp0[rt * 4 + r][0] = h0v * wo0;
        pp0[rt * 4 + r][1] = h0v * wo1;
      }
    }
    #pragma unroll
    for (int m = 0; m < 8; ++m) {
      pp0[m][0] = row_reduce16(pp0[m][0]);
      pp0[m][1] = row_reduce16(pp0[m][1]);
    }
    if (c16 == 0) {
      #pragma unroll
      for (int rt = 0; rt < 2; ++rt)
        #pragma unroll
        for (int r = 0; r < 4; ++r) {
          sh_pw0[w][(rt * 16 + q * 4 + r) * 2 + 0] = pp0[rt * 4 + r][0];
          sh_pw0[w][(rt * 16 + q * 4 + r) * 2 + 1] = pp0[rt * 4 + r][1];
        }
    }
  }
  __syncthreads();   // sA/sB reuse + pw0 visibility

  // ---- stage static_in = [ball(2), enc(128), pad] (32 rows, stride 168) ----
  for (int e = tid; e < BB * 168; e += 512) {
    int row = e / 168, col = e - row * 168;
    float x = (col < 2) ? ball[(size_t)(rbase + row) * 2 + col]
            : (col < 130) ? enc[(size_t)(rbase + row) * 128 + (col - 2)] : 0.f;
    unsigned short hb = f2bf(x);
    sh_sA[row * 168 + col] = hb;
    sh_sB[row * 168 + col] = f2bf(x - bf2f(hb));
  }
  // virtual pred_{-1} = h0 @ Wo.T + bo (t=0 feedback correction)
  if (tid < BB * 2) {
    float s = (tid & 1) ? bo1 : bo0;
    #pragma unroll
    for (int w2 = 0; w2 < 8; ++w2) s += sh_pw0[w2][tid];
    sh_p0[tid] = s;
  }
  __syncthreads();

  // ---- gate_static (3-product, K=160, SG-scaled) + biases, in REGISTERS ----
  f32x4 gacc[2][4] = {{{0.f,0.f,0.f,0.f},{0.f,0.f,0.f,0.f},{0.f,0.f,0.f,0.f},{0.f,0.f,0.f,0.f}},
                      {{0.f,0.f,0.f,0.f},{0.f,0.f,0.f,0.f},{0.f,0.f,0.f,0.f},{0.f,0.f,0.f,0.f}}};
  #pragma unroll
  for (int kt = 0; kt < 5; ++kt) {
    frag_u Ahi[2], Alo[2];
    #pragma unroll
    for (int rt = 0; rt < 2; ++rt) {
      Ahi[rt].u4 = *(const uint4*)&sh_sA[(rt * 16 + c16) * 168 + kt * 32 + q * 8];
      Alo[rt].u4 = *(const uint4*)&sh_sB[(rt * 16 + c16) * 168 + kt * 32 + q * 8];
    }
    #pragma unroll
    for (int g = 0; g < 4; ++g) {
      frag_u bhi, blo;
      #pragma unroll
      for (int j = 0; j < 8; ++j) {
        int kk = kt * 32 + q * 8 + j;
        float x = (kk < 130) ? SG[g] * W_ih[(size_t)(g * HDIM + colH) * 132 + 2 + kk] : 0.f;
        unsigned short hb = f2bf(x);
        bhi.s[j] = hb;
        blo.s[j] = f2bf(x - bf2f(hb));
      }
      #pragma unroll
      for (int rt = 0; rt < 2; ++rt) {
        gacc[rt][g] = MFMA(Ahi[rt].v, bhi.v, gacc[rt][g]);
        gacc[rt][g] = MFMA(Alo[rt].v, bhi.v, gacc[rt][g]);
        gacc[rt][g] = MFMA(Ahi[rt].v, blo.v, gacc[rt][g]);
      }
    }
  }
  // scaled feedback weights (t=0 correction operates in scaled units)
  float wps0[4], wps1[4];
  #pragma unroll
  for (int g = 0; g < 4; ++g) {
    int colG = g * HDIM + colH;
    float bb = SG[g] * (b_ih[colG] + b_hh[colG] + bo0 * wp0[g] + bo1 * wp1[g]);
    #pragma unroll
    for (int rt = 0; rt < 2; ++rt)
      #pragma unroll
      for (int r = 0; r < 4; ++r) gacc[rt][g][r] += bb;
    wps0[g] = SG[g] * wp0[g];
    wps1[g] = SG[g] * wp1[g];
  }

  // ---- phase-shifted time loop ----
  // Phase(G,t): MFMA group G gates at time t (reads h_G(t) = buf[t&1] rows G),
  //             then elementwise for group E=1-G consuming acc[E] (gates at
  //             tE = t-1+G), writing h_E(tE+1) -> buf[(t+G)&1] rows E.
  // One barrier per phase. acc[2][4] carries pending gates across the barrier.
  // pred[t-1] goes to sh_pred (LDS) -- NO global stores inside the loop, so
  // the barrier's implicit vmcnt(0) drain is a no-op in steady state.
  f32x4 acc[2][4];

  auto phase = [&](auto GC, int t, bool doEw, bool corr, bool doPred) {
    constexpr int G = decltype(GC)::value;
    constexpr int E = 1 - G;
    const int rbuf = t & 1;
    const __bf16* hp = &sh_h[rbuf][(G * 16 + c16) * STR];

    // --- MFMA gates for group G at time t (seeded by gate_static)
    frag_u A[4];
    #pragma unroll
    for (int kt = 0; kt < 4; ++kt)
      A[kt].u4 = *(const uint4*)(hp + kt * 32 + q * 8);
    #pragma unroll
    for (int g = 0; g < 4; ++g) acc[G][g] = gacc[G][g];
    #pragma unroll
    for (int kt = 0; kt < 4; ++kt)
      #pragma unroll
      for (int g = 0; g < 4; ++g)
        acc[G][g] = MFMA(A[kt].v, Wf[g][kt].v, acc[G][g]);

    // --- pred[t-1] rows G = h_G(t) @ Wo (wave 6 for A, wave 7 for B) -> LDS
    if (doPred && w == 6 + G) {
      f32x4 accP = {0.f, 0.f, 0.f, 0.f};
      #pragma unroll
      for (int kt = 0; kt < 4; ++kt) {
        frag_u wof;
        wof.u4 = sh_wof[kt * 64 + l];
        accP = MFMA(A[kt].v, wof.v, accP);
      }
      if (c16 < 2) {
        const int m0 = G * 16 + q * 4;
        const float bov = c16 ? bo1 : bo0;
        #pragma unroll
        for (int r = 0; r < 4; ++r)
          sh_pred[(m0 + r) * 256 + (t - 1) * 2 + c16] = accP[r] + bov;
      }
    }

    // --- elementwise for group E (independent of this phase's MFMAs)
    if (doEw) {
      if (corr) {  // gates at tE==0: remove folded pred_{-1} feedback (scaled)
        #pragma unroll
        for (int r = 0; r < 4; ++r) {
          float2 p0r = *(const float2*)&sh_p0[(E * 16 + q * 4 + r) * 2];
          #pragma unroll
          for (int g = 0; g < 4; ++g)
            acc[E][g][r] -= p0r.x * wps0[g] + p0r.y * wps1[g];
        }
      }
      __bf16* hwp = &sh_h[(t + G) & 1][(E * 16) * STR + colH];
      #pragma unroll
      for (int r = 0; r < 4; ++r) {
        float ei = EXP2(-acc[E][0][r]);          // e^{-i}
        float ef = EXP2(-acc[E][1][r]);          // e^{-f}
        float eg = EXP2(-acc[E][2][r]);          // e^{-2g}
        float eo = EXP2(-acc[E][3][r]);          // e^{-o}
        float t1 = (1.f + ei) * (1.f + eg);
        float pf = 1.f + ef;
        float num = cst[E][r] * t1 + (1.f - eg) * pf;
        float cv = num * RCP(t1 * pf);
        cst[E][r] = cv;
        float cc = fmaxf(cv, -15.f);             // only -inf side can overflow
        float ec = EXP2(cc * (-2.f * 1.4426950408889634f));
        float hv = (1.f - ec) * RCP((1.f + eo) * (1.f + ec));
        hwp[(q * 4 + r) * STR] = (__bf16)hv;
      }
    }
    __syncthreads();
  };

  phase(Int<0>{}, 0, false, false, false);   // MFMA A(0)
  phase(Int<1>{}, 0, true,  true,  false);   // MFMA B(0); ew A(0)+corr -> h_A(1)
  phase(Int<0>{}, 1, true,  true,  true);    // MFMA A(1); ew B(0)+corr -> h_B(1); pred[0]A
  for (int t = 1; t < 127; ++t) {
    phase(Int<1>{}, t,     true, false, true);   // MFMA B(t);   ew A(t)   -> h_A(t+1); pred[t-1]B
    phase(Int<0>{}, t + 1, true, false, true);   // MFMA A(t+1); ew B(t)   -> h_B(t+1); pred[t]A
  }
  phase(Int<1>{}, 127, true, false, true);   // MFMA B(127); ew A(127) -> h_A(128); pred[126]B

  // final elementwise: B(127) -> h_B(128) into buf[0]
  {
    __bf16* hwp = &sh_h[0][16 * STR + colH];
    #pragma unroll
    for (int r = 0; r < 4; ++r) {
      float ei = EXP2(-acc[1][0][r]);
      float ef = EXP2(-acc[1][1][r]);
      float eg = EXP2(-acc[1][2][r]);
      float eo = EXP2(-acc[1][3][r]);
      float t1 = (1.f + ei) * (1.f + eg);
      float pf = 1.f + ef;
      float num = cst[1][r] * t1 + (1.f - eg) * pf;
      float cv = num * RCP(t1 * pf);
      float cc = fmaxf(cv, -15.f);
      float ec = EXP2(cc * (-2.f * 1.4426950408889634f));
      float hv = (1.f - ec) * RCP((1.f + eo) * (1.f + ec));
      hwp[(q * 4 + r) * STR] = (__bf16)hv;
    }
  }
  __syncthreads();

  // ---- epilogue: pred[127] from h(128) (buf 0), waves 6 (A) / 7 (B) -> LDS ----
  if (w == 6 || w == 7) {
    const int Ge = w - 6;
    const __bf16* hp = &sh_h[0][(Ge * 16 + c16) * STR];
    f32x4 accP = {0.f, 0.f, 0.f, 0.f};
    #pragma unroll
    for (int kt = 0; kt < 4; ++kt) {
      frag_u A, wof;
      A.u4 = *(const uint4*)(hp + kt * 32 + q * 8);
      wof.u4 = sh_wof[kt * 64 + l];
      accP = MFMA(A.v, wof.v, accP);
    }
    if (c16 < 2) {
      const int m0 = Ge * 16 + q * 4;
      const float bov = c16 ? bo1 : bo0;
      #pragma unroll
      for (int r = 0; r < 4; ++r)
        sh_pred[(m0 + r) * 256 + 127 * 2 + c16] = accP[r] + bov;
    }
  }
  __syncthreads();

  // ---- bulk pred write: 32 KB LDS -> global, coalesced float4 ----
  for (int e = tid; e < BB * 64; e += 512) {
    int row = e >> 6, c4 = e & 63;
    *(float4*)&outp[(size_t)(rbase + row) * 256 + c4 * 4] =
        *(const float4*)&sh_pred[row * 256 + c4 * 4];
  }
}

extern "C" void kernel_launch(void* const* d_in, const int* in_sizes, int n_in,
                              void* d_out, int out_size, void* d_ws, size_t ws_size,
                              hipStream_t stream) {
  (void)in_sizes; (void)n_in; (void)d_ws; (void)ws_size; (void)out_size;
  const float* ctx  = (const float*)d_in[0];
  const float* enc  = (const float*)d_in[1];
  const float* ball = (const float*)d_in[2];
  // d_in[3] = max_frames (always 128)
  const float* Wh   = (const float*)d_in[4];
  const float* bh   = (const float*)d_in[5];
  const float* Wc   = (const float*)d_in[6];
  const float* bc   = (const float*)d_in[7];
  const float* W_ih = (const float*)d_in[8];
  const float* W_hh = (const float*)d_in[9];
  const float* b_ih = (const float*)d_in[10];
  const float* b_hh = (const float*)d_in[11];
  const float* Wo   = (const float*)d_in[12];
  const float* bo   = (const float*)d_in[13];
  float* outp = (float*)d_out;

  dim3 grid(256), block(512);
  traj_lstm<<<grid, block, 0, stream>>>(ctx, enc, ball, Wh, bh, Wc, bc,
                                        W_ih, W_hh, b_ih, b_hh, Wo, bo, outp);
}

// Round 9
// 299.437 us; speedup vs baseline: 1.6001x; 1.0433x over previous
//
#include <hip/hip_runtime.h>
#include <hip/hip_bf16.h>

// TrajectoryDecoder: B=8192 LSTM, T=128, H=128, CTX=256, IN_DIM=132.
// R19 = R13 (best, 260us) + VALU-count reduction in the phase body.
// R18 post-mortem: LDS-pred was WORSE (300us) -> in-loop global stores were
// never on the critical path; reverted. Across R10/R13/R17 the counters are
// invariant (VALU time ~127us, MFMA ~64us, dur ~260-270) -> scheduling
// attacks exhausted; the binding term is VALU issue (~2390 cy/SIMD/step).
// This round shrinks it directly:
//  1. MFMA C-seed consumed DIRECTLY (acc[G][g] = MFMA(A0, Wf, gacc[G][g]))
//     -> kills 32 explicit register copies per phase.
//  2. EW algebra packed as float2 pairs (r={0,1},{2,3} independent) ->
//     v_pk_fma/add/mul_f32 on gfx950 halve the non-trans VALU ops;
//     EXP2/RCP/fmax stay scalar (no packed trans).
// Everything else is R13 verbatim: 512 thr, 1 block/CU, launch_bounds(512,1),
// phase-shifted A/B row groups, one barrier/phase, reg gate_static,
// exp2-prescaled gates SG={L,L,2L,L}, in-loop global pred stores, t=0 corr.

#define HDIM 128
#define CTX_DIM 256
#define T_FRAMES 128
#define BB 32     // batch rows per block
#define STR 136   // h row stride (elements); 272B rows keep 16B alignment

typedef __bf16 bf16x8 __attribute__((ext_vector_type(8)));
typedef float  f32x4  __attribute__((ext_vector_type(4)));
typedef float  f32x2  __attribute__((ext_vector_type(2)));

union frag_u {
  bf16x8 v;
  unsigned short s[8];
  uint4 u4;
};

#if __has_builtin(__builtin_amdgcn_exp2f)
#define EXP2(x) __builtin_amdgcn_exp2f(x)
#else
#define EXP2(x) __expf((x) * 0.6931471805599453f)
#endif
#define RCP(x) __builtin_amdgcn_rcpf(x)

__device__ __forceinline__ unsigned short f2bf(float x) {
  unsigned u = __builtin_bit_cast(unsigned, x);
  u += 0x7FFFu + ((u >> 16) & 1u);          // RNE to bf16
  return (unsigned short)(u >> 16);
}
__device__ __forceinline__ float bf2f(unsigned short h) {
  unsigned u = ((unsigned)h) << 16;
  return __builtin_bit_cast(float, u);
}
template<int CTRL>
__device__ __forceinline__ float dpp_mov(float x) {
  return __builtin_bit_cast(float,
    __builtin_amdgcn_mov_dpp(__builtin_bit_cast(int, x), CTRL, 0xF, 0xF, true));
}
// sum over the 16-lane row group (setup-only)
__device__ __forceinline__ float row_reduce16(float v) {
  v += dpp_mov<0xB1>(v);     // quad_perm xor1
  v += dpp_mov<0x4E>(v);     // quad_perm xor2
  v += dpp_mov<0x124>(v);    // row_ror:4
  v += dpp_mov<0x128>(v);    // row_ror:8
  return v;
}

template<int N> struct Int { static constexpr int value = N; };

#define MFMA(a, b, c) __builtin_amdgcn_mfma_f32_16x16x32_bf16((a), (b), (c), 0, 0, 0)

__global__ __launch_bounds__(512, 1) void traj_lstm(
    const float* __restrict__ ctx, const float* __restrict__ enc,
    const float* __restrict__ ball,
    const float* __restrict__ Wh, const float* __restrict__ bh,
    const float* __restrict__ Wc, const float* __restrict__ bc,
    const float* __restrict__ W_ih, const float* __restrict__ W_hh,
    const float* __restrict__ b_ih, const float* __restrict__ b_hh,
    const float* __restrict__ Wo, const float* __restrict__ bo,
    float* __restrict__ outp)
{
  __shared__ __align__(16) __bf16 sh_h[2][BB * STR];          // h double buffer (17.4 KB)
  __shared__ __align__(16) unsigned short sh_sA[BB * 264];    // setup staging hi (16.9 KB)
  __shared__ __align__(16) unsigned short sh_sB[BB * 264];    // setup staging lo (16.9 KB)
  __shared__ __align__(16) uint4 sh_wof[4 * 64];              // Wo B-frags (4 KB)
  __shared__ float sh_pw0[8][BB * 2];     // setup pred partials (2 KB)
  __shared__ float sh_p0[BB * 2];         // virtual pred_{-1} for t=0 correction

  const int tid  = threadIdx.x;
  const int w    = tid >> 6;
  const int l    = tid & 63;
  const int q    = l >> 4;
  const int c16  = l & 15;
  const int colH = w * 16 + c16;
  const int rbase = blockIdx.x * BB;

  const float Lc = 1.4426950408889634f;          // log2(e)
  const float SG[4] = {Lc, Lc, 2.f * Lc, Lc};    // i, f, g, o exp2 prescales
  const float bo0 = bo[0], bo1 = bo[1];
  const float wo0 = Wo[colH], wo1 = Wo[HDIM + colH];

  // feedback weights per gate (W_prev columns)
  float wp0[4], wp1[4];
  #pragma unroll
  for (int g = 0; g < 4; ++g) {
    wp0[g] = W_ih[(size_t)(g * HDIM + colH) * 132 + 0];
    wp1[g] = W_ih[(size_t)(g * HDIM + colH) * 132 + 1];
  }

  // ---- persistent W_eff fragments: SG[g]*(W_hh + wp0*Wo0 + wp1*Wo1) ----
  frag_u Wf[4][4];                  // [gate][ktile]  (64 VGPRs)
  #pragma unroll
  for (int kt = 0; kt < 4; ++kt) {
    const float* w0p = Wo + kt * 32 + q * 8;
    const float* w1p = Wo + HDIM + kt * 32 + q * 8;
    float4 a0 = *(const float4*)w0p, a1 = *(const float4*)(w0p + 4);
    float4 b0 = *(const float4*)w1p, b1 = *(const float4*)(w1p + 4);
    float wo0v[8] = {a0.x, a0.y, a0.z, a0.w, a1.x, a1.y, a1.z, a1.w};
    float wo1v[8] = {b0.x, b0.y, b0.z, b0.w, b1.x, b1.y, b1.z, b1.w};
    #pragma unroll
    for (int g = 0; g < 4; ++g) {
      const float* wr = W_hh + (size_t)(g * HDIM + colH) * HDIM + kt * 32 + q * 8;
      float4 f0 = *(const float4*)wr;
      float4 f1 = *(const float4*)(wr + 4);
      float ff[8] = {f0.x, f0.y, f0.z, f0.w, f1.x, f1.y, f1.z, f1.w};
      #pragma unroll
      for (int j = 0; j < 8; ++j)
        Wf[g][kt].s[j] = f2bf(SG[g] * (ff[j] + wp0[g] * wo0v[j] + wp1[g] * wo1v[j]));
    }
  }

  // ---- Wo B-fragments for the pred MFMA -> LDS (waves 6/7 read) ----
  #pragma unroll
  for (int kt = 0; kt < 4; ++kt) {
    frag_u wf;
    #pragma unroll
    for (int j = 0; j < 8; ++j) {
      float x = (c16 < 2) ? Wo[c16 * HDIM + kt * 32 + q * 8 + j] : 0.f;
      wf.s[j] = f2bf(x);
    }
    if (w == 0) sh_wof[kt * 64 + l] = wf.u4;
  }

  // ---- stage context rows (32 rows, hi/lo bf16, stride 264) ----
  for (int e = tid; e < BB * 256; e += 512) {
    int row = e >> 8, col = e & 255;
    float x = ctx[(size_t)(rbase + row) * CTX_DIM + col];
    unsigned short hb = f2bf(x);
    sh_sA[row * 264 + col] = hb;
    sh_sB[row * 264 + col] = f2bf(x - bf2f(hb));
  }
  __syncthreads();

  // ---- h0/c0 = ctx @ Wh.T/Wc.T + bias (3-product split, K=256, 2 groups) ----
  float cst[2][4];   // [group][r]  (raw units)
  {
    f32x4 aH[2] = {{0.f,0.f,0.f,0.f},{0.f,0.f,0.f,0.f}};
    f32x4 aC[2] = {{0.f,0.f,0.f,0.f},{0.f,0.f,0.f,0.f}};
    #pragma unroll
    for (int kt = 0; kt < 8; ++kt) {
      frag_u Ahi[2], Alo[2];
      #pragma unroll
      for (int rt = 0; rt < 2; ++rt) {
        Ahi[rt].u4 = *(const uint4*)&sh_sA[(rt * 16 + c16) * 264 + kt * 32 + q * 8];
        Alo[rt].u4 = *(const uint4*)&sh_sB[(rt * 16 + c16) * 264 + kt * 32 + q * 8];
      }
      frag_u bhi, blo;
      {
        const float* wr = Wh + (size_t)colH * CTX_DIM + kt * 32 + q * 8;
        float4 f0 = *(const float4*)wr;
        float4 f1 = *(const float4*)(wr + 4);
        float ff[8] = {f0.x, f0.y, f0.z, f0.w, f1.x, f1.y, f1.z, f1.w};
        #pragma unroll
        for (int j = 0; j < 8; ++j) {
          unsigned short hb = f2bf(ff[j]);
          bhi.s[j] = hb;
          blo.s[j] = f2bf(ff[j] - bf2f(hb));
        }
      }
      #pragma unroll
      for (int rt = 0; rt < 2; ++rt) {
        aH[rt] = MFMA(Ahi[rt].v, bhi.v, aH[rt]);
        aH[rt] = MFMA(Alo[rt].v, bhi.v, aH[rt]);
        aH[rt] = MFMA(Ahi[rt].v, blo.v, aH[rt]);
      }
      {
        const float* wr = Wc + (size_t)colH * CTX_DIM + kt * 32 + q * 8;
        float4 f0 = *(const float4*)wr;
        float4 f1 = *(const float4*)(wr + 4);
        float ff[8] = {f0.x, f0.y, f0.z, f0.w, f1.x, f1.y, f1.z, f1.w};
        #pragma unroll
        for (int j = 0; j < 8; ++j) {
          unsigned short hb = f2bf(ff[j]);
          bhi.s[j] = hb;
          blo.s[j] = f2bf(ff[j] - bf2f(hb));
        }
      }
      #pragma unroll
      for (int rt = 0; rt < 2; ++rt) {
        aC[rt] = MFMA(Ahi[rt].v, bhi.v, aC[rt]);
        aC[rt] = MFMA(Alo[rt].v, bhi.v, aC[rt]);
        aC[rt] = MFMA(Ahi[rt].v, blo.v, aC[rt]);
      }
    }
    float bhv = bh[colH], bcv = bc[colH];
    float pp0[8][2];
    #pragma unroll
    for (int rt = 0; rt < 2; ++rt) {
      #pragma unroll
      for (int r = 0; r < 4; ++r) {
        float h0v = aH[rt][r] + bhv;
        cst[rt][r] = aC[rt][r] + bcv;
        sh_h[0][(rt * 16 + q * 4 + r) * STR + colH] = (__bf16)h0v;
        pp0[rt * 4 + r][0] = h0v * wo0;
        pp0[rt * 4 + r][1] = h0v * wo1;
      }
    }
    #pragma unroll
    for (int m = 0; m < 8; ++m) {
      pp0[m][0] = row_reduce16(pp0[m][0]);
      pp0[m][1] = row_reduce16(pp0[m][1]);
    }
    if (c16 == 0) {
      #pragma unroll
      for (int rt = 0; rt < 2; ++rt)
        #pragma unroll
        for (int r = 0; r < 4; ++r) {
          sh_pw0[w][(rt * 16 + q * 4 + r) * 2 + 0] = pp0[rt * 4 + r][0];
          sh_pw0[w][(rt * 16 + q * 4 + r) * 2 + 1] = pp0[rt * 4 + r][1];
        }
    }
  }
  __syncthreads();   // sA/sB reuse + pw0 visibility

  // ---- stage static_in = [ball(2), enc(128), pad] (32 rows, stride 168) ----
  for (int e = tid; e < BB * 168; e += 512) {
    int row = e / 168, col = e - row * 168;
    float x = (col < 2) ? ball[(size_t)(rbase + row) * 2 + col]
            : (col < 130) ? enc[(size_t)(rbase + row) * 128 + (col - 2)] : 0.f;
    unsigned short hb = f2bf(x);
    sh_sA[row * 168 + col] = hb;
    sh_sB[row * 168 + col] = f2bf(x - bf2f(hb));
  }
  // virtual pred_{-1} = h0 @ Wo.T + bo (t=0 feedback correction)
  if (tid < BB * 2) {
    float s = (tid & 1) ? bo1 : bo0;
    #pragma unroll
    for (int w2 = 0; w2 < 8; ++w2) s += sh_pw0[w2][tid];
    sh_p0[tid] = s;
  }
  __syncthreads();

  // ---- gate_static (3-product, K=160, SG-scaled) + biases, in REGISTERS ----
  f32x4 gacc[2][4] = {{{0.f,0.f,0.f,0.f},{0.f,0.f,0.f,0.f},{0.f,0.f,0.f,0.f},{0.f,0.f,0.f,0.f}},
                      {{0.f,0.f,0.f,0.f},{0.f,0.f,0.f,0.f},{0.f,0.f,0.f,0.f},{0.f,0.f,0.f,0.f}}};
  #pragma unroll
  for (int kt = 0; kt < 5; ++kt) {
    frag_u Ahi[2], Alo[2];
    #pragma unroll
    for (int rt = 0; rt < 2; ++rt) {
      Ahi[rt].u4 = *(const uint4*)&sh_sA[(rt * 16 + c16) * 168 + kt * 32 + q * 8];
      Alo[rt].u4 = *(const uint4*)&sh_sB[(rt * 16 + c16) * 168 + kt * 32 + q * 8];
    }
    #pragma unroll
    for (int g = 0; g < 4; ++g) {
      frag_u bhi, blo;
      #pragma unroll
      for (int j = 0; j < 8; ++j) {
        int kk = kt * 32 + q * 8 + j;
        float x = (kk < 130) ? SG[g] * W_ih[(size_t)(g * HDIM + colH) * 132 + 2 + kk] : 0.f;
        unsigned short hb = f2bf(x);
        bhi.s[j] = hb;
        blo.s[j] = f2bf(x - bf2f(hb));
      }
      #pragma unroll
      for (int rt = 0; rt < 2; ++rt) {
        gacc[rt][g] = MFMA(Ahi[rt].v, bhi.v, gacc[rt][g]);
        gacc[rt][g] = MFMA(Alo[rt].v, bhi.v, gacc[rt][g]);
        gacc[rt][g] = MFMA(Ahi[rt].v, blo.v, gacc[rt][g]);
      }
    }
  }
  // scaled feedback weights (t=0 correction operates in scaled units)
  float wps0[4], wps1[4];
  #pragma unroll
  for (int g = 0; g < 4; ++g) {
    int colG = g * HDIM + colH;
    float bb = SG[g] * (b_ih[colG] + b_hh[colG] + bo0 * wp0[g] + bo1 * wp1[g]);
    #pragma unroll
    for (int rt = 0; rt < 2; ++rt)
      #pragma unroll
      for (int r = 0; r < 4; ++r) gacc[rt][g][r] += bb;
    wps0[g] = SG[g] * wp0[g];
    wps1[g] = SG[g] * wp1[g];
  }

  // ---- phase-shifted time loop ----
  // Phase(G,t): MFMA group G gates at time t (reads h_G(t) = buf[t&1] rows G),
  //             then elementwise for group E=1-G consuming acc[E] (gates at
  //             tE = t-1+G), writing h_E(tE+1) -> buf[(t+G)&1] rows E.
  // One barrier per phase. acc[2][4] carries pending gates across the barrier.
  f32x4 acc[2][4];

  auto phase = [&](auto GC, int t, bool doEw, bool corr, bool doPred) {
    constexpr int G = decltype(GC)::value;
    constexpr int E = 1 - G;
    const int rbuf = t & 1;
    const __bf16* hp = &sh_h[rbuf][(G * 16 + c16) * STR];

    // --- MFMA gates for group G at time t; kt=0 consumes gate_static seed
    //     DIRECTLY as the MFMA C operand (no register copy).
    frag_u A[4];
    #pragma unroll
    for (int kt = 0; kt < 4; ++kt)
      A[kt].u4 = *(const uint4*)(hp + kt * 32 + q * 8);
    #pragma unroll
    for (int g = 0; g < 4; ++g)
      acc[G][g] = MFMA(A[0].v, Wf[g][0].v, gacc[G][g]);
    #pragma unroll
    for (int kt = 1; kt < 4; ++kt)
      #pragma unroll
      for (int g = 0; g < 4; ++g)
        acc[G][g] = MFMA(A[kt].v, Wf[g][kt].v, acc[G][g]);

    // --- pred[t-1] rows G = h_G(t) @ Wo (wave 6 for A, wave 7 for B)
    if (doPred && w == 6 + G) {
      f32x4 accP = {0.f, 0.f, 0.f, 0.f};
      #pragma unroll
      for (int kt = 0; kt < 4; ++kt) {
        frag_u wof;
        wof.u4 = sh_wof[kt * 64 + l];
        accP = MFMA(A[kt].v, wof.v, accP);
      }
      if (c16 < 2) {
        const int m0 = G * 16 + q * 4;
        const float bov = c16 ? bo1 : bo0;
        #pragma unroll
        for (int r = 0; r < 4; ++r)
          outp[(size_t)(rbase + m0 + r) * (T_FRAMES * 2) + (t - 1) * 2 + c16] = accP[r] + bov;
      }
    }

    // --- elementwise for group E (independent of this phase's MFMAs)
    //     trans scalar, algebra packed as float2 pairs (v_pk_* on gfx950)
    if (doEw) {
      if (corr) {  // gates at tE==0: remove folded pred_{-1} feedback (scaled)
        #pragma unroll
        for (int r = 0; r < 4; ++r) {
          float2 p0r = *(const float2*)&sh_p0[(E * 16 + q * 4 + r) * 2];
          #pragma unroll
          for (int g = 0; g < 4; ++g)
            acc[E][g][r] -= p0r.x * wps0[g] + p0r.y * wps1[g];
        }
      }
      __bf16* hwp = &sh_h[(t + G) & 1][(E * 16) * STR + colH];
      #pragma unroll
      for (int pr = 0; pr < 2; ++pr) {
        const int r0 = pr * 2, r1 = pr * 2 + 1;
        f32x2 ei = { EXP2(-acc[E][0][r0]), EXP2(-acc[E][0][r1]) };   // e^{-i}
        f32x2 ef = { EXP2(-acc[E][1][r0]), EXP2(-acc[E][1][r1]) };   // e^{-f}
        f32x2 eg = { EXP2(-acc[E][2][r0]), EXP2(-acc[E][2][r1]) };   // e^{-2g}
        f32x2 eo = { EXP2(-acc[E][3][r0]), EXP2(-acc[E][3][r1]) };   // e^{-o}
        f32x2 t1 = (1.f + ei) * (1.f + eg);
        f32x2 pf = 1.f + ef;
        f32x2 cp = { cst[E][r0], cst[E][r1] };
        f32x2 num = cp * t1 + (1.f - eg) * pf;
        f32x2 den = t1 * pf;
        f32x2 cv = num * (f32x2){ RCP(den.x), RCP(den.y) };
        cst[E][r0] = cv.x;
        cst[E][r1] = cv.y;
        f32x2 cc = { fmaxf(cv.x, -15.f), fmaxf(cv.y, -15.f) };       // -inf guard
        cc = cc * (-2.f * 1.4426950408889634f);
        f32x2 ec = { EXP2(cc.x), EXP2(cc.y) };
        f32x2 d2 = (1.f + eo) * (1.f + ec);
        f32x2 hv = (1.f - ec) * (f32x2){ RCP(d2.x), RCP(d2.y) };
        hwp[(q * 4 + r0) * STR] = (__bf16)hv.x;
        hwp[(q * 4 + r1) * STR] = (__bf16)hv.y;
      }
    }
    __syncthreads();
  };

  phase(Int<0>{}, 0, false, false, false);   // MFMA A(0)
  phase(Int<1>{}, 0, true,  true,  false);   // MFMA B(0); ew A(0)+corr -> h_A(1)
  phase(Int<0>{}, 1, true,  true,  true);    // MFMA A(1); ew B(0)+corr -> h_B(1); pred[0]A
  for (int t = 1; t < 127; ++t) {
    phase(Int<1>{}, t,     true, false, true);   // MFMA B(t);   ew A(t)   -> h_A(t+1); pred[t-1]B
    phase(Int<0>{}, t + 1, true, false, true);   // MFMA A(t+1); ew B(t)   -> h_B(t+1); pred[t]A
  }
  phase(Int<1>{}, 127, true, false, true);   // MFMA B(127); ew A(127) -> h_A(128); pred[126]B

  // final elementwise: B(127) -> h_B(128) into buf[0]
  {
    __bf16* hwp = &sh_h[0][16 * STR + colH];
    #pragma unroll
    for (int r = 0; r < 4; ++r) {
      float ei = EXP2(-acc[1][0][r]);
      float ef = EXP2(-acc[1][1][r]);
      float eg = EXP2(-acc[1][2][r]);
      float eo = EXP2(-acc[1][3][r]);
      float t1 = (1.f + ei) * (1.f + eg);
      float pf = 1.f + ef;
      float num = cst[1][r] * t1 + (1.f - eg) * pf;
      float cv = num * RCP(t1 * pf);
      float cc = fmaxf(cv, -15.f);
      float ec = EXP2(cc * (-2.f * 1.4426950408889634f));
      float hv = (1.f - ec) * RCP((1.f + eo) * (1.f + ec));
      hwp[(q * 4 + r) * STR] = (__bf16)hv;
    }
  }
  __syncthreads();

  // ---- epilogue: pred[127] from h(128) (buf 0), waves 6 (A) / 7 (B) ----
  if (w == 6 || w == 7) {
    const int Ge = w - 6;
    const __bf16* hp = &sh_h[0][(Ge * 16 + c16) * STR];
    f32x4 accP = {0.f, 0.f, 0.f, 0.f};
    #pragma unroll
    for (int kt = 0; kt < 4; ++kt) {
      frag_u A, wof;
      A.u4 = *(const uint4*)(hp + kt * 32 + q * 8);
      wof.u4 = sh_wof[kt * 64 + l];
      accP = MFMA(A.v, wof.v, accP);
    }
    if (c16 < 2) {
      const int m0 = Ge * 16 + q * 4;
      const float bov = c16 ? bo1 : bo0;
      #pragma unroll
      for (int r = 0; r < 4; ++r)
        outp[(size_t)(rbase + m0 + r) * (T_FRAMES * 2) + 127 * 2 + c16] = accP[r] + bov;
    }
  }
}

extern "C" void kernel_launch(void* const* d_in, const int* in_sizes, int n_in,
                              void* d_out, int out_size, void* d_ws, size_t ws_size,
                              hipStream_t stream) {
  (void)in_sizes; (void)n_in; (void)d_ws; (void)ws_size; (void)out_size;
  const float* ctx  = (const float*)d_in[0];
  const float* enc  = (const float*)d_in[1];
  const float* ball = (const float*)d_in[2];
  // d_in[3] = max_frames (always 128)
  const float* Wh   = (const float*)d_in[4];
  const float* bh   = (const float*)d_in[5];
  const float* Wc   = (const float*)d_in[6];
  const float* bc   = (const float*)d_in[7];
  const float* W_ih = (const float*)d_in[8];
  const float* W_hh = (const float*)d_in[9];
  const float* b_ih = (const float*)d_in[10];
  const float* b_hh = (const float*)d_in[11];
  const float* Wo   = (const float*)d_in[12];
  const float* bo   = (const float*)d_in[13];
  float* outp = (float*)d_out;

  dim3 grid(256), block(512);
  traj_lstm<<<grid, block, 0, stream>>>(ctx, enc, ball, Wh, bh, Wc, bc,
                                        W_ih, W_hh, b_ih, b_hh, Wo, bo, outp);
}

// Round 10
// 296.172 us; speedup vs baseline: 1.6177x; 1.0110x over previous
//
#include <hip/hip_runtime.h>
#include <hip/hip_bf16.h>

// TrajectoryDecoder: B=8192 LSTM, T=128, H=128, CTX=256, IN_DIM=132.
// R20 = R19 (253us, best) + compile-time buffer parity + setprio.
// R19 post-mortem: VALU-count cut worked (VALU time 127->116us, dur -7us)
// -> VALU issue is (partially) binding. Remaining cheap cuts:
//  1. RBUF as a template param (R10 had this; lost in the R13 rewrite):
//     the t-loop runs 4 phases/iteration with STATIC buffer parity, so
//     every sh_h base is a compile-time constant -> kills per-phase
//     address recomputation VALU.
//  2. s_setprio(1) around the MFMA cluster, (0) for EW (T5): waves 6/7
//     (pred straggler) vs 0-5 diverge within a phase -> mild role
//     diversity; m218b/m191 show setprio pays in that regime, zero cost
//     if null.
// Everything else is R19 verbatim: 512 thr, 1 block/CU, launch_bounds(512,1),
// phase-shifted A/B groups, one barrier/phase, direct MFMA C-seed,
// float2-packed EW, exp2 prescale SG={L,L,2L,L}, in-loop pred stores.

#define HDIM 128
#define CTX_DIM 256
#define T_FRAMES 128
#define BB 32     // batch rows per block
#define STR 136   // h row stride (elements); 272B rows keep 16B alignment

typedef __bf16 bf16x8 __attribute__((ext_vector_type(8)));
typedef float  f32x4  __attribute__((ext_vector_type(4)));
typedef float  f32x2  __attribute__((ext_vector_type(2)));

union frag_u {
  bf16x8 v;
  unsigned short s[8];
  uint4 u4;
};

#if __has_builtin(__builtin_amdgcn_exp2f)
#define EXP2(x) __builtin_amdgcn_exp2f(x)
#else
#define EXP2(x) __expf((x) * 0.6931471805599453f)
#endif
#define RCP(x) __builtin_amdgcn_rcpf(x)

__device__ __forceinline__ unsigned short f2bf(float x) {
  unsigned u = __builtin_bit_cast(unsigned, x);
  u += 0x7FFFu + ((u >> 16) & 1u);          // RNE to bf16
  return (unsigned short)(u >> 16);
}
__device__ __forceinline__ float bf2f(unsigned short h) {
  unsigned u = ((unsigned)h) << 16;
  return __builtin_bit_cast(float, u);
}
template<int CTRL>
__device__ __forceinline__ float dpp_mov(float x) {
  return __builtin_bit_cast(float,
    __builtin_amdgcn_mov_dpp(__builtin_bit_cast(int, x), CTRL, 0xF, 0xF, true));
}
// sum over the 16-lane row group (setup-only)
__device__ __forceinline__ float row_reduce16(float v) {
  v += dpp_mov<0xB1>(v);     // quad_perm xor1
  v += dpp_mov<0x4E>(v);     // quad_perm xor2
  v += dpp_mov<0x124>(v);    // row_ror:4
  v += dpp_mov<0x128>(v);    // row_ror:8
  return v;
}

template<int N> struct Int { static constexpr int value = N; };

#define MFMA(a, b, c) __builtin_amdgcn_mfma_f32_16x16x32_bf16((a), (b), (c), 0, 0, 0)

__global__ __launch_bounds__(512, 1) void traj_lstm(
    const float* __restrict__ ctx, const float* __restrict__ enc,
    const float* __restrict__ ball,
    const float* __restrict__ Wh, const float* __restrict__ bh,
    const float* __restrict__ Wc, const float* __restrict__ bc,
    const float* __restrict__ W_ih, const float* __restrict__ W_hh,
    const float* __restrict__ b_ih, const float* __restrict__ b_hh,
    const float* __restrict__ Wo, const float* __restrict__ bo,
    float* __restrict__ outp)
{
  __shared__ __align__(16) __bf16 sh_h[2][BB * STR];          // h double buffer (17.4 KB)
  __shared__ __align__(16) unsigned short sh_sA[BB * 264];    // setup staging hi (16.9 KB)
  __shared__ __align__(16) unsigned short sh_sB[BB * 264];    // setup staging lo (16.9 KB)
  __shared__ __align__(16) uint4 sh_wof[4 * 64];              // Wo B-frags (4 KB)
  __shared__ float sh_pw0[8][BB * 2];     // setup pred partials (2 KB)
  __shared__ float sh_p0[BB * 2];         // virtual pred_{-1} for t=0 correction

  const int tid  = threadIdx.x;
  const int w    = tid >> 6;
  const int l    = tid & 63;
  const int q    = l >> 4;
  const int c16  = l & 15;
  const int colH = w * 16 + c16;
  const int rbase = blockIdx.x * BB;

  const float Lc = 1.4426950408889634f;          // log2(e)
  const float SG[4] = {Lc, Lc, 2.f * Lc, Lc};    // i, f, g, o exp2 prescales
  const float bo0 = bo[0], bo1 = bo[1];
  const float wo0 = Wo[colH], wo1 = Wo[HDIM + colH];

  // feedback weights per gate (W_prev columns)
  float wp0[4], wp1[4];
  #pragma unroll
  for (int g = 0; g < 4; ++g) {
    wp0[g] = W_ih[(size_t)(g * HDIM + colH) * 132 + 0];
    wp1[g] = W_ih[(size_t)(g * HDIM + colH) * 132 + 1];
  }

  // ---- persistent W_eff fragments: SG[g]*(W_hh + wp0*Wo0 + wp1*Wo1) ----
  frag_u Wf[4][4];                  // [gate][ktile]  (64 VGPRs)
  #pragma unroll
  for (int kt = 0; kt < 4; ++kt) {
    const float* w0p = Wo + kt * 32 + q * 8;
    const float* w1p = Wo + HDIM + kt * 32 + q * 8;
    float4 a0 = *(const float4*)w0p, a1 = *(const float4*)(w0p + 4);
    float4 b0 = *(const float4*)w1p, b1 = *(const float4*)(w1p + 4);
    float wo0v[8] = {a0.x, a0.y, a0.z, a0.w, a1.x, a1.y, a1.z, a1.w};
    float wo1v[8] = {b0.x, b0.y, b0.z, b0.w, b1.x, b1.y, b1.z, b1.w};
    #pragma unroll
    for (int g = 0; g < 4; ++g) {
      const float* wr = W_hh + (size_t)(g * HDIM + colH) * HDIM + kt * 32 + q * 8;
      float4 f0 = *(const float4*)wr;
      float4 f1 = *(const float4*)(wr + 4);
      float ff[8] = {f0.x, f0.y, f0.z, f0.w, f1.x, f1.y, f1.z, f1.w};
      #pragma unroll
      for (int j = 0; j < 8; ++j)
        Wf[g][kt].s[j] = f2bf(SG[g] * (ff[j] + wp0[g] * wo0v[j] + wp1[g] * wo1v[j]));
    }
  }

  // ---- Wo B-fragments for the pred MFMA -> LDS (waves 6/7 read) ----
  #pragma unroll
  for (int kt = 0; kt < 4; ++kt) {
    frag_u wf;
    #pragma unroll
    for (int j = 0; j < 8; ++j) {
      float x = (c16 < 2) ? Wo[c16 * HDIM + kt * 32 + q * 8 + j] : 0.f;
      wf.s[j] = f2bf(x);
    }
    if (w == 0) sh_wof[kt * 64 + l] = wf.u4;
  }

  // ---- stage context rows (32 rows, hi/lo bf16, stride 264) ----
  for (int e = tid; e < BB * 256; e += 512) {
    int row = e >> 8, col = e & 255;
    float x = ctx[(size_t)(rbase + row) * CTX_DIM + col];
    unsigned short hb = f2bf(x);
    sh_sA[row * 264 + col] = hb;
    sh_sB[row * 264 + col] = f2bf(x - bf2f(hb));
  }
  __syncthreads();

  // ---- h0/c0 = ctx @ Wh.T/Wc.T + bias (3-product split, K=256, 2 groups) ----
  float cst[2][4];   // [group][r]  (raw units)
  {
    f32x4 aH[2] = {{0.f,0.f,0.f,0.f},{0.f,0.f,0.f,0.f}};
    f32x4 aC[2] = {{0.f,0.f,0.f,0.f},{0.f,0.f,0.f,0.f}};
    #pragma unroll
    for (int kt = 0; kt < 8; ++kt) {
      frag_u Ahi[2], Alo[2];
      #pragma unroll
      for (int rt = 0; rt < 2; ++rt) {
        Ahi[rt].u4 = *(const uint4*)&sh_sA[(rt * 16 + c16) * 264 + kt * 32 + q * 8];
        Alo[rt].u4 = *(const uint4*)&sh_sB[(rt * 16 + c16) * 264 + kt * 32 + q * 8];
      }
      frag_u bhi, blo;
      {
        const float* wr = Wh + (size_t)colH * CTX_DIM + kt * 32 + q * 8;
        float4 f0 = *(const float4*)wr;
        float4 f1 = *(const float4*)(wr + 4);
        float ff[8] = {f0.x, f0.y, f0.z, f0.w, f1.x, f1.y, f1.z, f1.w};
        #pragma unroll
        for (int j = 0; j < 8; ++j) {
          unsigned short hb = f2bf(ff[j]);
          bhi.s[j] = hb;
          blo.s[j] = f2bf(ff[j] - bf2f(hb));
        }
      }
      #pragma unroll
      for (int rt = 0; rt < 2; ++rt) {
        aH[rt] = MFMA(Ahi[rt].v, bhi.v, aH[rt]);
        aH[rt] = MFMA(Alo[rt].v, bhi.v, aH[rt]);
        aH[rt] = MFMA(Ahi[rt].v, blo.v, aH[rt]);
      }
      {
        const float* wr = Wc + (size_t)colH * CTX_DIM + kt * 32 + q * 8;
        float4 f0 = *(const float4*)wr;
        float4 f1 = *(const float4*)(wr + 4);
        float ff[8] = {f0.x, f0.y, f0.z, f0.w, f1.x, f1.y, f1.z, f1.w};
        #pragma unroll
        for (int j = 0; j < 8; ++j) {
          unsigned short hb = f2bf(ff[j]);
          bhi.s[j] = hb;
          blo.s[j] = f2bf(ff[j] - bf2f(hb));
        }
      }
      #pragma unroll
      for (int rt = 0; rt < 2; ++rt) {
        aC[rt] = MFMA(Ahi[rt].v, bhi.v, aC[rt]);
        aC[rt] = MFMA(Alo[rt].v, bhi.v, aC[rt]);
        aC[rt] = MFMA(Ahi[rt].v, blo.v, aC[rt]);
      }
    }
    float bhv = bh[colH], bcv = bc[colH];
    float pp0[8][2];
    #pragma unroll
    for (int rt = 0; rt < 2; ++rt) {
      #pragma unroll
      for (int r = 0; r < 4; ++r) {
        float h0v = aH[rt][r] + bhv;
        cst[rt][r] = aC[rt][r] + bcv;
        sh_h[0][(rt * 16 + q * 4 + r) * STR + colH] = (__bf16)h0v;
        pp0[rt * 4 + r][0] = h0v * wo0;
        pp0[rt * 4 + r][1] = h0v * wo1;
      }
    }
    #pragma unroll
    for (int m = 0; m < 8; ++m) {
      pp0[m][0] = row_reduce16(pp0[m][0]);
      pp0[m][1] = row_reduce16(pp0[m][1]);
    }
    if (c16 == 0) {
      #pragma unroll
      for (int rt = 0; rt < 2; ++rt)
        #pragma unroll
        for (int r = 0; r < 4; ++r) {
          sh_pw0[w][(rt * 16 + q * 4 + r) * 2 + 0] = pp0[rt * 4 + r][0];
          sh_pw0[w][(rt * 16 + q * 4 + r) * 2 + 1] = pp0[rt * 4 + r][1];
        }
    }
  }
  __syncthreads();   // sA/sB reuse + pw0 visibility

  // ---- stage static_in = [ball(2), enc(128), pad] (32 rows, stride 168) ----
  for (int e = tid; e < BB * 168; e += 512) {
    int row = e / 168, col = e - row * 168;
    float x = (col < 2) ? ball[(size_t)(rbase + row) * 2 + col]
            : (col < 130) ? enc[(size_t)(rbase + row) * 128 + (col - 2)] : 0.f;
    unsigned short hb = f2bf(x);
    sh_sA[row * 168 + col] = hb;
    sh_sB[row * 168 + col] = f2bf(x - bf2f(hb));
  }
  // virtual pred_{-1} = h0 @ Wo.T + bo (t=0 feedback correction)
  if (tid < BB * 2) {
    float s = (tid & 1) ? bo1 : bo0;
    #pragma unroll
    for (int w2 = 0; w2 < 8; ++w2) s += sh_pw0[w2][tid];
    sh_p0[tid] = s;
  }
  __syncthreads();

  // ---- gate_static (3-product, K=160, SG-scaled) + biases, in REGISTERS ----
  f32x4 gacc[2][4] = {{{0.f,0.f,0.f,0.f},{0.f,0.f,0.f,0.f},{0.f,0.f,0.f,0.f},{0.f,0.f,0.f,0.f}},
                      {{0.f,0.f,0.f,0.f},{0.f,0.f,0.f,0.f},{0.f,0.f,0.f,0.f},{0.f,0.f,0.f,0.f}}};
  #pragma unroll
  for (int kt = 0; kt < 5; ++kt) {
    frag_u Ahi[2], Alo[2];
    #pragma unroll
    for (int rt = 0; rt < 2; ++rt) {
      Ahi[rt].u4 = *(const uint4*)&sh_sA[(rt * 16 + c16) * 168 + kt * 32 + q * 8];
      Alo[rt].u4 = *(const uint4*)&sh_sB[(rt * 16 + c16) * 168 + kt * 32 + q * 8];
    }
    #pragma unroll
    for (int g = 0; g < 4; ++g) {
      frag_u bhi, blo;
      #pragma unroll
      for (int j = 0; j < 8; ++j) {
        int kk = kt * 32 + q * 8 + j;
        float x = (kk < 130) ? SG[g] * W_ih[(size_t)(g * HDIM + colH) * 132 + 2 + kk] : 0.f;
        unsigned short hb = f2bf(x);
        bhi.s[j] = hb;
        blo.s[j] = f2bf(x - bf2f(hb));
      }
      #pragma unroll
      for (int rt = 0; rt < 2; ++rt) {
        gacc[rt][g] = MFMA(Ahi[rt].v, bhi.v, gacc[rt][g]);
        gacc[rt][g] = MFMA(Alo[rt].v, bhi.v, gacc[rt][g]);
        gacc[rt][g] = MFMA(Ahi[rt].v, blo.v, gacc[rt][g]);
      }
    }
  }
  // scaled feedback weights (t=0 correction operates in scaled units)
  float wps0[4], wps1[4];
  #pragma unroll
  for (int g = 0; g < 4; ++g) {
    int colG = g * HDIM + colH;
    float bb = SG[g] * (b_ih[colG] + b_hh[colG] + bo0 * wp0[g] + bo1 * wp1[g]);
    #pragma unroll
    for (int rt = 0; rt < 2; ++rt)
      #pragma unroll
      for (int r = 0; r < 4; ++r) gacc[rt][g][r] += bb;
    wps0[g] = SG[g] * wp0[g];
    wps1[g] = SG[g] * wp1[g];
  }

  // ---- phase-shifted time loop, compile-time buffer parity ----
  // Phase<G,RBUF>(t): MFMA group G gates at time t (reads sh_h[RBUF] rows G),
  //   EW for E=1-G consuming acc[E], writing h_E -> sh_h[(RBUF+G)&1] rows E.
  // One barrier per phase. acc[2][4] carries pending gates across the barrier.
  f32x4 acc[2][4];

  auto phase = [&](auto GC, auto RC, int t, bool doEw, bool corr, bool doPred) {
    constexpr int G = decltype(GC)::value;
    constexpr int E = 1 - G;
    constexpr int RBUF = decltype(RC)::value;
    constexpr int WB = (RBUF + G) & 1;
    const __bf16* hp = &sh_h[RBUF][(G * 16 + c16) * STR];

    // --- MFMA gates for group G at time t; kt=0 consumes gate_static seed
    //     DIRECTLY as the MFMA C operand (no register copy).
    frag_u A[4];
    #pragma unroll
    for (int kt = 0; kt < 4; ++kt)
      A[kt].u4 = *(const uint4*)(hp + kt * 32 + q * 8);
    __builtin_amdgcn_s_setprio(1);
    #pragma unroll
    for (int g = 0; g < 4; ++g)
      acc[G][g] = MFMA(A[0].v, Wf[g][0].v, gacc[G][g]);
    #pragma unroll
    for (int kt = 1; kt < 4; ++kt)
      #pragma unroll
      for (int g = 0; g < 4; ++g)
        acc[G][g] = MFMA(A[kt].v, Wf[g][kt].v, acc[G][g]);

    // --- pred[t-1] rows G = h_G(t) @ Wo (wave 6 for A, wave 7 for B)
    if (doPred && w == 6 + G) {
      f32x4 accP = {0.f, 0.f, 0.f, 0.f};
      #pragma unroll
      for (int kt = 0; kt < 4; ++kt) {
        frag_u wof;
        wof.u4 = sh_wof[kt * 64 + l];
        accP = MFMA(A[kt].v, wof.v, accP);
      }
      if (c16 < 2) {
        const int m0 = G * 16 + q * 4;
        const float bov = c16 ? bo1 : bo0;
        #pragma unroll
        for (int r = 0; r < 4; ++r)
          outp[(size_t)(rbase + m0 + r) * (T_FRAMES * 2) + (t - 1) * 2 + c16] = accP[r] + bov;
      }
    }
    __builtin_amdgcn_s_setprio(0);

    // --- elementwise for group E (independent of this phase's MFMAs)
    //     trans scalar, algebra packed as float2 pairs (v_pk_* on gfx950)
    if (doEw) {
      if (corr) {  // gates at tE==0: remove folded pred_{-1} feedback (scaled)
        #pragma unroll
        for (int r = 0; r < 4; ++r) {
          float2 p0r = *(const float2*)&sh_p0[(E * 16 + q * 4 + r) * 2];
          #pragma unroll
          for (int g = 0; g < 4; ++g)
            acc[E][g][r] -= p0r.x * wps0[g] + p0r.y * wps1[g];
        }
      }
      __bf16* hwp = &sh_h[WB][(E * 16) * STR + colH];
      #pragma unroll
      for (int pr = 0; pr < 2; ++pr) {
        const int r0 = pr * 2, r1 = pr * 2 + 1;
        f32x2 ei = { EXP2(-acc[E][0][r0]), EXP2(-acc[E][0][r1]) };   // e^{-i}
        f32x2 ef = { EXP2(-acc[E][1][r0]), EXP2(-acc[E][1][r1]) };   // e^{-f}
        f32x2 eg = { EXP2(-acc[E][2][r0]), EXP2(-acc[E][2][r1]) };   // e^{-2g}
        f32x2 eo = { EXP2(-acc[E][3][r0]), EXP2(-acc[E][3][r1]) };   // e^{-o}
        f32x2 t1 = (1.f + ei) * (1.f + eg);
        f32x2 pf = 1.f + ef;
        f32x2 cp = { cst[E][r0], cst[E][r1] };
        f32x2 num = cp * t1 + (1.f - eg) * pf;
        f32x2 den = t1 * pf;
        f32x2 cv = num * (f32x2){ RCP(den.x), RCP(den.y) };
        cst[E][r0] = cv.x;
        cst[E][r1] = cv.y;
        f32x2 cc = { fmaxf(cv.x, -15.f), fmaxf(cv.y, -15.f) };       // -inf guard
        cc = cc * (-2.f * 1.4426950408889634f);
        f32x2 ec = { EXP2(cc.x), EXP2(cc.y) };
        f32x2 d2 = (1.f + eo) * (1.f + ec);
        f32x2 hv = (1.f - ec) * (f32x2){ RCP(d2.x), RCP(d2.y) };
        hwp[(q * 4 + r0) * STR] = (__bf16)hv.x;
        hwp[(q * 4 + r1) * STR] = (__bf16)hv.y;
      }
    }
    __syncthreads();
  };

  phase(Int<0>{}, Int<0>{}, 0, false, false, false);   // MFMA A(0)
  phase(Int<1>{}, Int<0>{}, 0, true,  true,  false);   // MFMA B(0); ew A(0)+corr -> h_A(1)
  phase(Int<0>{}, Int<1>{}, 1, true,  true,  true);    // MFMA A(1); ew B(0)+corr -> h_B(1); pred[0]A
  for (int tp = 0; tp < 63; ++tp) {
    const int t = 2 * tp + 1;
    phase(Int<1>{}, Int<1>{}, t,     true, false, true);   // MFMA B(t);   ew A(t)   -> h_A(t+1)
    phase(Int<0>{}, Int<0>{}, t + 1, true, false, true);   // MFMA A(t+1); ew B(t)   -> h_B(t+1)
    phase(Int<1>{}, Int<0>{}, t + 1, true, false, true);   // MFMA B(t+1); ew A(t+1) -> h_A(t+2)
    phase(Int<0>{}, Int<1>{}, t + 2, true, false, true);   // MFMA A(t+2); ew B(t+1) -> h_B(t+2)
  }
  phase(Int<1>{}, Int<1>{}, 127, true, false, true);   // MFMA B(127); ew A(127) -> h_A(128); pred[126]B

  // final elementwise: B(127) -> h_B(128) into buf[0]
  {
    __bf16* hwp = &sh_h[0][16 * STR + colH];
    #pragma unroll
    for (int r = 0; r < 4; ++r) {
      float ei = EXP2(-acc[1][0][r]);
      float ef = EXP2(-acc[1][1][r]);
      float eg = EXP2(-acc[1][2][r]);
      float eo = EXP2(-acc[1][3][r]);
      float t1 = (1.f + ei) * (1.f + eg);
      float pf = 1.f + ef;
      float num = cst[1][r] * t1 + (1.f - eg) * pf;
      float cv = num * RCP(t1 * pf);
      float cc = fmaxf(cv, -15.f);
      float ec = EXP2(cc * (-2.f * 1.4426950408889634f));
      float hv = (1.f - ec) * RCP((1.f + eo) * (1.f + ec));
      hwp[(q * 4 + r) * STR] = (__bf16)hv;
    }
  }
  __syncthreads();

  // ---- epilogue: pred[127] from h(128) (buf 0), waves 6 (A) / 7 (B) ----
  if (w == 6 || w == 7) {
    const int Ge = w - 6;
    const __bf16* hp = &sh_h[0][(Ge * 16 + c16) * STR];
    f32x4 accP = {0.f, 0.f, 0.f, 0.f};
    #pragma unroll
    for (int kt = 0; kt < 4; ++kt) {
      frag_u A, wof;
      A.u4 = *(const uint4*)(hp + kt * 32 + q * 8);
      wof.u4 = sh_wof[kt * 64 + l];
      accP = MFMA(A.v, wof.v, accP);
    }
    if (c16 < 2) {
      const int m0 = Ge * 16 + q * 4;
      const float bov = c16 ? bo1 : bo0;
      #pragma unroll
      for (int r = 0; r < 4; ++r)
        outp[(size_t)(rbase + m0 + r) * (T_FRAMES * 2) + 127 * 2 + c16] = accP[r] + bov;
    }
  }
}

extern "C" void kernel_launch(void* const* d_in, const int* in_sizes, int n_in,
                              void* d_out, int out_size, void* d_ws, size_t ws_size,
                              hipStream_t stream) {
  (void)in_sizes; (void)n_in; (void)d_ws; (void)ws_size; (void)out_size;
  const float* ctx  = (const float*)d_in[0];
  const float* enc  = (const float*)d_in[1];
  const float* ball = (const float*)d_in[2];
  // d_in[3] = max_frames (always 128)
  const float* Wh   = (const float*)d_in[4];
  const float* bh   = (const float*)d_in[5];
  const float* Wc   = (const float*)d_in[6];
  const float* bc   = (const float*)d_in[7];
  const float* W_ih = (const float*)d_in[8];
  const float* W_hh = (const float*)d_in[9];
  const float* b_ih = (const float*)d_in[10];
  const float* b_hh = (const float*)d_in[11];
  const float* Wo   = (const float*)d_in[12];
  const float* bo   = (const float*)d_in[13];
  float* outp = (float*)d_out;

  dim3 grid(256), block(512);
  traj_lstm<<<grid, block, 0, stream>>>(ctx, enc, ball, Wh, bh, Wc, bc,
                                        W_ih, W_hh, b_ih, b_hh, Wo, bo, outp);
}